// Round 4
// baseline (226.813 us; speedup 1.0000x reference)
//
#include <hip/hip_runtime.h>

#define ALPHA_LEAKY 0.2f
#define EPS_F 1e-10f

#define BSHIFT 7            // bucket = 128 qi
#define BRANGE 128
#define NBMAX 1024          // max buckets (Nq <= 131072)
#define CHUNK 16384         // edges per bin_kernel block
#define KBUF_CAP 3072       // bucket LDS capacity (avg 2048, +22 sigma)
#define HIST_BLOCKS 512
#define WLD 68              // W LDS row stride (dwords): 16B-aligned, uniform banks

__device__ __forceinline__ float readlane_f(float v, int lane) {
  return __int_as_float(__builtin_amdgcn_readlane(__float_as_int(v), lane));
}

// RNE float -> bf16
__device__ __forceinline__ unsigned short f2bf(float x) {
  unsigned int u = __float_as_uint(x);
  return (unsigned short)((u + 0x7fffu + ((u >> 16) & 1u)) >> 16);
}

// ---------------------------------------------------------------------------
// hist_kernel: LDS histogram of qi>>BSHIFT -> gcnt. SPLIT from the old fused
// hist_proj_kernel: rounds 0-3 produced four different proj implementations
// all pinned at 63-70us; fused counters could not attribute hist vs proj.
// Separate dispatches give per-phase dur_us/VALUBusy/FETCH.
// ---------------------------------------------------------------------------
__global__ __launch_bounds__(256) void hist_kernel(
    const int* __restrict__ eq, int* __restrict__ gcnt, int E, int NB) {
  const int t = threadIdx.x;
  __shared__ int lcnt[NBMAX];
  for (int i = t; i < NBMAX; i += 256) lcnt[i] = 0;
  __syncthreads();
  const int n4 = E >> 2;
  for (int i = blockIdx.x * 256 + t; i < n4; i += HIST_BLOCKS * 256) {
    const int4 q = ((const int4*)eq)[i];
    atomicAdd(&lcnt[q.x >> BSHIFT], 1);
    atomicAdd(&lcnt[q.y >> BSHIFT], 1);
    atomicAdd(&lcnt[q.z >> BSHIFT], 1);
    atomicAdd(&lcnt[q.w >> BSHIFT], 1);
  }
  if (blockIdx.x == 0 && t < (E & 3))
    atomicAdd(&lcnt[eq[(n4 << 2) + t] >> BSHIFT], 1);
  __syncthreads();
  for (int i = t; i < NB; i += 256)
    if (lcnt[i]) atomicAdd(&gcnt[i], lcnt[i]);
}

// ---------------------------------------------------------------------------
// proj_kernel: fold + q/k gemv + kv projection (round-3 structure: W staged
// in LDS [64][WLD], 8 nodes per wave-iter, 1 ds_read_b128 per 4-dim chunk,
// readlane x-broadcast; sk folded as x.uk + ck).
// ---------------------------------------------------------------------------
__global__ __launch_bounds__(256) void proj_kernel(
    const float* __restrict__ qnodes, const float* __restrict__ kvnodes,
    const float* __restrict__ W, const float* __restrict__ pb,
    const float* __restrict__ aw, unsigned int* __restrict__ Kp16,
    float* __restrict__ sq, float* __restrict__ sk,
    int Nq, int Nk, int projBlocks) {
  const int t = threadIdx.x;
  __shared__ __align__(16) float Ws[64 * WLD];
  __shared__ float pt0[256];
  __shared__ float pt1[256];
  __shared__ __align__(16) float us[64];
  __shared__ __align__(16) float uk[64];
  __shared__ float cq_s, ck_s;
  const int lane = t & 63;
  const int waveId = blockIdx.x * 4 + (t >> 6);
  const int nWaves = projBlocks * 4;

  // stage W -> LDS [64][WLD]
  for (int i = t; i < 4096; i += 256) Ws[(i >> 6) * WLD + (i & 63)] = W[i];
  __syncthreads();

  // fold: us = W^T aw_q, uk = W^T aw_k (256-thread partial sums, 16 o's each)
  {
    const int pd = t & 63, og = t >> 6;
    float s0 = 0.f, s1 = 0.f;
#pragma unroll
    for (int oo = 0; oo < 16; ++oo) {
      const int o = og * 16 + oo;
      const float wv = Ws[o * WLD + pd];
      s0 = fmaf(aw[o], wv, s0);
      s1 = fmaf(aw[64 + o], wv, s1);
    }
    pt0[t] = s0;
    pt1[t] = s1;
  }
  __syncthreads();
  if (t < 64) {
    us[t] = (pt0[t] + pt0[t + 64]) + (pt0[t + 128] + pt0[t + 192]);
    uk[t] = (pt1[t] + pt1[t + 64]) + (pt1[t + 128] + pt1[t + 192]);
    if (t == 0) {
      float c0 = 0.f, c1 = 0.f;
      for (int o = 0; o < 64; ++o) {
        c0 = fmaf(aw[o], pb[o], c0);
        c1 = fmaf(aw[64 + o], pb[o], c1);
      }
      cq_s = c0;
      ck_s = c1;
    }
  }
  __syncthreads();

  // q-side gemv: sq[n] = qnodes[n,:].us + cq (4 nodes per wave-iter)
  {
    const int sub = lane & 15, ng = lane >> 4;
    const float4 uv = ((const float4*)us)[sub];
    const float c = cq_s;
    for (int base = waveId * 4; base < Nq; base += nWaves * 4) {
      const int n = base + ng;
      float s = 0.f;
      if (n < Nq) {
        const float4 x = *(const float4*)(qnodes + (size_t)n * 64 + sub * 4);
        s = x.x * uv.x + x.y * uv.y + x.z * uv.z + x.w * uv.w;
      }
#pragma unroll
      for (int off = 1; off <= 8; off <<= 1) s += __shfl_xor(s, off, 64);
      if (sub == 0 && n < Nq) sq[n] = s + c;
    }
  }

  // k-side folded gemv: sk[n] = kvnodes[n,:].uk + ck
  {
    const int sub = lane & 15, ng = lane >> 4;
    const float4 uv = ((const float4*)uk)[sub];
    const float c = ck_s;
    for (int base = waveId * 4; base < Nk; base += nWaves * 4) {
      const int n = base + ng;
      float s = 0.f;
      if (n < Nk) {
        const float4 x = *(const float4*)(kvnodes + (size_t)n * 64 + sub * 4);
        s = x.x * uv.x + x.y * uv.y + x.z * uv.z + x.w * uv.w;
      }
#pragma unroll
      for (int off = 1; off <= 8; off <<= 1) s += __shfl_xor(s, off, 64);
      if (sub == 0 && n < Nk) sk[n] = s + c;
    }
  }

  // kv projection: 8 nodes per wave-iteration. lane = output dim o.
  const float bl = pb[lane];
  const int ngroups = (Nk + 7) >> 3;
  for (int g = waveId; g < ngroups; g += nWaves) {
    const int n0 = g << 3;
    const float* xb = kvnodes + (size_t)n0 * 64 + lane;
    const float x0 = (n0 + 0 < Nk) ? xb[0 * 64] : 0.f;
    const float x1 = (n0 + 1 < Nk) ? xb[1 * 64] : 0.f;
    const float x2 = (n0 + 2 < Nk) ? xb[2 * 64] : 0.f;
    const float x3 = (n0 + 3 < Nk) ? xb[3 * 64] : 0.f;
    const float x4 = (n0 + 4 < Nk) ? xb[4 * 64] : 0.f;
    const float x5 = (n0 + 5 < Nk) ? xb[5 * 64] : 0.f;
    const float x6 = (n0 + 6 < Nk) ? xb[6 * 64] : 0.f;
    const float x7 = (n0 + 7 < Nk) ? xb[7 * 64] : 0.f;

    float acc[8];
#pragma unroll
    for (int j = 0; j < 8; ++j) acc[j] = bl;

#pragma unroll
    for (int c = 0; c < 16; ++c) {
      const float4 wv = *(const float4*)(Ws + lane * WLD + c * 4);
#define KSTEP(J, XJ)                                        \
  acc[J] = fmaf(readlane_f(XJ, 4 * c + 0), wv.x, acc[J]);   \
  acc[J] = fmaf(readlane_f(XJ, 4 * c + 1), wv.y, acc[J]);   \
  acc[J] = fmaf(readlane_f(XJ, 4 * c + 2), wv.z, acc[J]);   \
  acc[J] = fmaf(readlane_f(XJ, 4 * c + 3), wv.w, acc[J]);
      KSTEP(0, x0) KSTEP(1, x1) KSTEP(2, x2) KSTEP(3, x3)
      KSTEP(4, x4) KSTEP(5, x5) KSTEP(6, x6) KSTEP(7, x7)
#undef KSTEP
    }

    // pack pairs of output dims to bf16x2, store 128B/node (32 even lanes)
#pragma unroll
    for (int j = 0; j < 8; ++j) {
      const float nb = __shfl_xor(acc[j], 1, 64);
      if (!(lane & 1) && (n0 + j) < Nk)
        Kp16[(size_t)(n0 + j) * 32 + (lane >> 1)] =
            ((unsigned int)f2bf(nb) << 16) | f2bf(acc[j]);
    }
  }
}

// ---------------------------------------------------------------------------
// bucket_scan: exclusive scan of gcnt[0..NB) -> gbase, gcursor. NB <= 1024.
// ---------------------------------------------------------------------------
__global__ __launch_bounds__(1024) void bucket_scan(
    const int* __restrict__ gcnt, int* __restrict__ gbase,
    int* __restrict__ gcursor, int NB) {
  __shared__ int wso[16];
  const int t = threadIdx.x, lane = t & 63, wv = t >> 6;
  const int v = (t < NB) ? gcnt[t] : 0;
  int x = v;
#pragma unroll
  for (int off = 1; off < 64; off <<= 1) {
    const int y = __shfl_up(x, off, 64);
    if (lane >= off) x += y;
  }
  if (lane == 63) wso[wv] = x;
  __syncthreads();
  int woff = 0;
  for (int w = 0; w < wv; ++w) woff += wso[w];
  const int excl = woff + x - v;
  if (t < NB) { gbase[t] = excl; gcursor[t] = excl; }
}

// ---------------------------------------------------------------------------
// bin_kernel: 1024 threads, 16384 edges/block: coalesced int4 reads into
// registers, LDS per-bucket count, ONE reservation atomic per bucket per
// block, (qi,ki) pairs written in ~168B contiguous runs.
// ---------------------------------------------------------------------------
__global__ __launch_bounds__(1024) void bin_kernel(
    const int* __restrict__ eq, const int* __restrict__ ek,
    int* __restrict__ gcursor, int2* __restrict__ pairs, int E, int NB) {
  __shared__ int lcnt[NBMAX];
  __shared__ int lbase[NBMAX];
  const int t = threadIdx.x;
  for (int i = t; i < NBMAX; i += 1024) lcnt[i] = 0;
  __syncthreads();

  const int cbase = blockIdx.x * CHUNK;
  int4 qv[4], kv[4];
#pragma unroll
  for (int j = 0; j < 4; ++j) {
    const int e0 = cbase + (((j << 10) + t) << 2);
    if (e0 + 3 < E) {
      qv[j] = *(const int4*)(eq + e0);
      kv[j] = *(const int4*)(ek + e0);
    } else {
      int tq[4] = {-1, -1, -1, -1}, tk[4] = {0, 0, 0, 0};
      for (int r = 0; r < 4; ++r)
        if (e0 + r < E) { tq[r] = eq[e0 + r]; tk[r] = ek[e0 + r]; }
      qv[j] = make_int4(tq[0], tq[1], tq[2], tq[3]);
      kv[j] = make_int4(tk[0], tk[1], tk[2], tk[3]);
    }
    if (qv[j].x >= 0) atomicAdd(&lcnt[qv[j].x >> BSHIFT], 1);
    if (qv[j].y >= 0) atomicAdd(&lcnt[qv[j].y >> BSHIFT], 1);
    if (qv[j].z >= 0) atomicAdd(&lcnt[qv[j].z >> BSHIFT], 1);
    if (qv[j].w >= 0) atomicAdd(&lcnt[qv[j].w >> BSHIFT], 1);
  }
  __syncthreads();
  for (int i = t; i < NB; i += 1024) {
    lbase[i] = lcnt[i] ? atomicAdd(&gcursor[i], lcnt[i]) : 0;
    lcnt[i] = 0;
  }
  __syncthreads();
#pragma unroll
  for (int j = 0; j < 4; ++j) {
    const int qs[4] = {qv[j].x, qv[j].y, qv[j].z, qv[j].w};
    const int ks[4] = {kv[j].x, kv[j].y, kv[j].z, kv[j].w};
#pragma unroll
    for (int r = 0; r < 4; ++r) {
      if (qs[r] >= 0) {
        const int b = qs[r] >> BSHIFT;
        pairs[lbase[b] + atomicAdd(&lcnt[b], 1)] = make_int2(qs[r], ks[r]);
      }
    }
  }
}

// ---------------------------------------------------------------------------
// sort_agg_kernel: one 512-thr block per 128-qi bucket (782 blocks ~3/CU).
// Phase A: register-cache the bucket's pairs, LDS counting-sort ki -> kibuf.
// Phase B (TRANSPOSED): lane = (node-sub ng 0..7, dim-group dg 0..7); each
// lane owns 8 dims of one node and walks that node's full edge list (2x
// unrolled). NO cross-lane reduction, no edge-slot padding: wsum is computed
// redundantly by the node's 8 lanes; each lane stores its own 32B directly
// (256B contiguous per node across its 8 lanes).
// ---------------------------------------------------------------------------
__global__ __launch_bounds__(512, 6) void sort_agg_kernel(
    const int2* __restrict__ pairs, const int* __restrict__ gcnt,
    const int* __restrict__ gbase, const float* __restrict__ sq,
    const float* __restrict__ sk, const float* __restrict__ ab,
    const unsigned int* __restrict__ Kp16, float* __restrict__ out,
    int Nq) {
  __shared__ int lcnt[BRANGE];
  __shared__ int lcur[BRANGE];
  __shared__ int lstart[BRANGE + 1];
  __shared__ int kibuf[KBUF_CAP];
  __shared__ int wso2[2];

  const int t = threadIdx.x;
  const int b = blockIdx.x;
  const int qlo = b << BSHIFT;
  int n = gcnt[b];
  if (n > KBUF_CAP) n = KBUF_CAP;  // statistically never; OOB guard
  const int base = gbase[b];

  if (t < BRANGE) lcnt[t] = 0;
  __syncthreads();

  // cache this thread's pairs (<= 6 at KBUF_CAP 3072)
  int2 pv[6];
  int np = 0;
#pragma unroll
  for (int r = 0; r < 6; ++r) {
    const int i = t + (r << 9);
    if (i < n) { pv[r] = pairs[base + i]; ++np; }
  }
#pragma unroll
  for (int r = 0; r < 6; ++r)
    if (r < np) atomicAdd(&lcnt[pv[r].x - qlo], 1);
  __syncthreads();

  // exclusive scan of lcnt[0..127] (first 2 waves)
  const int lane = t & 63, wv = t >> 6;
  int v = 0, x = 0;
  if (t < BRANGE) {
    v = lcnt[t];
    x = v;
#pragma unroll
    for (int off = 1; off < 64; off <<= 1) {
      const int y = __shfl_up(x, off, 64);
      if (lane >= off) x += y;
    }
    if (lane == 63) wso2[wv] = x;
  }
  __syncthreads();
  if (t < BRANGE) {
    const int excl = ((wv == 1) ? wso2[0] : 0) + x - v;
    lstart[t] = excl;
    lcur[t] = excl;
    if (t == BRANGE - 1) lstart[BRANGE] = excl + v;
  }
  __syncthreads();

  // scatter ki into kibuf (sorted by local qi)
#pragma unroll
  for (int r = 0; r < 6; ++r)
    if (r < np) kibuf[atomicAdd(&lcur[pv[r].x - qlo], 1)] = pv[r].y;
  __syncthreads();

  // Phase B: transposed aggregation. 8 waves x 8 nodes = 64 nodes per pass.
  const int ng = lane >> 3, dg = lane & 7;
  const float abv = ab[0];
#pragma unroll
  for (int pass = 0; pass < 2; ++pass) {
    const int l = (pass << 6) + (wv << 3) + ng;
    const int node = qlo + l;
    const bool act = node < Nq;
    const int s = act ? lstart[l] : 0;
    const int e = act ? lstart[l + 1] : 0;
    const float sqn = act ? sq[node] + abv : 0.f;

    float acc[8] = {0.f, 0.f, 0.f, 0.f, 0.f, 0.f, 0.f, 0.f};
    float wsum = 0.f;
    int j = s;
    for (; j + 1 < e; j += 2) {
      const int k1 = kibuf[j];
      const int k2 = kibuf[j + 1];
      float x1 = sqn + sk[k1];
      float x2 = sqn + sk[k2];
      x1 = x1 > 0.f ? x1 : ALPHA_LEAKY * x1;
      x2 = x2 > 0.f ? x2 : ALPHA_LEAKY * x2;
      const float w1 = __expf(x1);
      const float w2 = __expf(x2);
      const uint4 u1 = *(const uint4*)(Kp16 + (size_t)k1 * 32 + (dg << 2));
      const uint4 u2 = *(const uint4*)(Kp16 + (size_t)k2 * 32 + (dg << 2));
      acc[0] = fmaf(w1, __uint_as_float(u1.x << 16), acc[0]);
      acc[1] = fmaf(w1, __uint_as_float(u1.x & 0xffff0000u), acc[1]);
      acc[2] = fmaf(w1, __uint_as_float(u1.y << 16), acc[2]);
      acc[3] = fmaf(w1, __uint_as_float(u1.y & 0xffff0000u), acc[3]);
      acc[4] = fmaf(w1, __uint_as_float(u1.z << 16), acc[4]);
      acc[5] = fmaf(w1, __uint_as_float(u1.z & 0xffff0000u), acc[5]);
      acc[6] = fmaf(w1, __uint_as_float(u1.w << 16), acc[6]);
      acc[7] = fmaf(w1, __uint_as_float(u1.w & 0xffff0000u), acc[7]);
      acc[0] = fmaf(w2, __uint_as_float(u2.x << 16), acc[0]);
      acc[1] = fmaf(w2, __uint_as_float(u2.x & 0xffff0000u), acc[1]);
      acc[2] = fmaf(w2, __uint_as_float(u2.y << 16), acc[2]);
      acc[3] = fmaf(w2, __uint_as_float(u2.y & 0xffff0000u), acc[3]);
      acc[4] = fmaf(w2, __uint_as_float(u2.z << 16), acc[4]);
      acc[5] = fmaf(w2, __uint_as_float(u2.z & 0xffff0000u), acc[5]);
      acc[6] = fmaf(w2, __uint_as_float(u2.w << 16), acc[6]);
      acc[7] = fmaf(w2, __uint_as_float(u2.w & 0xffff0000u), acc[7]);
      wsum += w1 + w2;
    }
    if (j < e) {
      const int k1 = kibuf[j];
      float x1 = sqn + sk[k1];
      x1 = x1 > 0.f ? x1 : ALPHA_LEAKY * x1;
      const float w1 = __expf(x1);
      const uint4 u1 = *(const uint4*)(Kp16 + (size_t)k1 * 32 + (dg << 2));
      acc[0] = fmaf(w1, __uint_as_float(u1.x << 16), acc[0]);
      acc[1] = fmaf(w1, __uint_as_float(u1.x & 0xffff0000u), acc[1]);
      acc[2] = fmaf(w1, __uint_as_float(u1.y << 16), acc[2]);
      acc[3] = fmaf(w1, __uint_as_float(u1.y & 0xffff0000u), acc[3]);
      acc[4] = fmaf(w1, __uint_as_float(u1.z << 16), acc[4]);
      acc[5] = fmaf(w1, __uint_as_float(u1.z & 0xffff0000u), acc[5]);
      acc[6] = fmaf(w1, __uint_as_float(u1.w << 16), acc[6]);
      acc[7] = fmaf(w1, __uint_as_float(u1.w & 0xffff0000u), acc[7]);
      wsum += w1;
    }
    if (act) {
      const float inv = 1.0f / (wsum + EPS_F);
      float4 r0 = {acc[0] * inv, acc[1] * inv, acc[2] * inv, acc[3] * inv};
      float4 r1 = {acc[4] * inv, acc[5] * inv, acc[6] * inv, acc[7] * inv};
      float* o = out + (size_t)node * 64 + (dg << 3);
      *(float4*)o = r0;
      *(float4*)(o + 4) = r1;
    }
  }
}

extern "C" void kernel_launch(void* const* d_in, const int* in_sizes, int n_in,
                              void* d_out, int out_size, void* d_ws, size_t ws_size,
                              hipStream_t stream) {
  const float* qnodes = (const float*)d_in[0];   // (Nq, 64) f32
  const float* kvnodes = (const float*)d_in[1];  // (Nk, 64) f32
  const int* ei = (const int*)d_in[2];           // (2, E) int32
  const float* W = (const float*)d_in[3];        // (64, 64)
  const float* pb = (const float*)d_in[4];       // (64,)
  const float* aw = (const float*)d_in[5];       // (1, 128): [wq | wk]
  const float* ab = (const float*)d_in[6];       // (1,)

  const int Nq = in_sizes[0] / 64;
  const int Nk = in_sizes[1] / 64;
  const int E = in_sizes[2] / 2;
  const int NB = (Nq + BRANGE - 1) >> BSHIFT;    // 782 at Nq=100000

  const int* eq = ei;
  const int* ek = ei + E;

  // --- workspace layout ---
  char* ws = (char*)d_ws;
  int2* pairs = (int2*)ws;                              // E int2
  unsigned int* Kp16 = (unsigned int*)(pairs + E);      // Nk*32 words
  float* sq = (float*)(Kp16 + (size_t)Nk * 32);         // Nq
  float* sk = sq + Nq;                                  // Nk
  int* gcnt = (int*)(sk + Nk);                          // NBMAX
  int* gbase = gcnt + NBMAX;                            // NBMAX
  int* gcursor = gbase + NBMAX;                         // NBMAX

  hipMemsetAsync(gcnt, 0, NBMAX * sizeof(int), stream);

  // --- hist and proj as SEPARATE dispatches (attribution + full-grid each) ---
  hist_kernel<<<HIST_BLOCKS, 256, 0, stream>>>(eq, gcnt, E, NB);

  const int projBlocks = 1536;
  proj_kernel<<<projBlocks, 256, 0, stream>>>(qnodes, kvnodes, W, pb, aw,
                                              Kp16, sq, sk, Nq, Nk,
                                              projBlocks);

  // --- scan + binning ---
  bucket_scan<<<1, 1024, 0, stream>>>(gcnt, gbase, gcursor, NB);
  bin_kernel<<<(E + CHUNK - 1) / CHUNK, 1024, 0, stream>>>(eq, ek, gcursor,
                                                           pairs, E, NB);

  // --- fused bucket sort + transposed aggregation ---
  sort_agg_kernel<<<NB, 512, 0, stream>>>(pairs, gcnt, gbase, sq, sk, ab,
                                          Kp16, (float*)d_out, Nq);
}

// Round 5
// 193.831 us; speedup vs baseline: 1.1702x; 1.1702x over previous
//
#include <hip/hip_runtime.h>

#define ALPHA_LEAKY 0.2f
#define EPS_F 1e-10f

#define BSHIFT 7            // bucket = 128 qi
#define BRANGE 128
#define NBMAX 1024          // max buckets (Nq <= 131072)
#define CHUNK 16384         // edges per bin_kernel block
#define KBUF_CAP 3072       // bucket LDS capacity (avg 2048, +22 sigma)
#define HIST_BLOCKS 512

using half4_t = __attribute__((ext_vector_type(4))) _Float16;
using f32x4 = __attribute__((ext_vector_type(4))) float;

// RNE float -> bf16
__device__ __forceinline__ unsigned short f2bf(float x) {
  unsigned int u = __float_as_uint(x);
  return (unsigned short)((u + 0x7fffu + ((u >> 16) & 1u)) >> 16);
}

// ---------------------------------------------------------------------------
// hist_kernel: LDS histogram of qi>>BSHIFT -> gcnt.
// ---------------------------------------------------------------------------
__global__ __launch_bounds__(256) void hist_kernel(
    const int* __restrict__ eq, int* __restrict__ gcnt, int E, int NB) {
  const int t = threadIdx.x;
  __shared__ int lcnt[NBMAX];
  for (int i = t; i < NBMAX; i += 256) lcnt[i] = 0;
  __syncthreads();
  const int n4 = E >> 2;
  for (int i = blockIdx.x * 256 + t; i < n4; i += HIST_BLOCKS * 256) {
    const int4 q = ((const int4*)eq)[i];
    atomicAdd(&lcnt[q.x >> BSHIFT], 1);
    atomicAdd(&lcnt[q.y >> BSHIFT], 1);
    atomicAdd(&lcnt[q.z >> BSHIFT], 1);
    atomicAdd(&lcnt[q.w >> BSHIFT], 1);
  }
  if (blockIdx.x == 0 && t < (E & 3))
    atomicAdd(&lcnt[eq[(n4 << 2) + t] >> BSHIFT], 1);
  __syncthreads();
  for (int i = t; i < NB; i += 256)
    if (lcnt[i]) atomicAdd(&gcnt[i], lcnt[i]);
}

// ---------------------------------------------------------------------------
// proj_kernel v2: MFMA projection.
// Rounds 0-4 evidence: every VALU-structured fp32 projection (LDS-walk,
// remat, spill, readlane outer-product) lands at 63-70us, VALUBusy ~57%,
// MfmaUtil 0 -- the vector pipe cannot stream a 100k x (64x64) GEMM.
// This is matmul-shaped (K=64 >= 16) -> matrix cores (Guideline 10).
//
// v_mfma_f32_16x16x16f16, textbook CDNA fragment layout:
//   A[m][k]: m=l&15, k=(l>>4)*4+j   (lane loads 4 contiguous dims of node m)
//   B[k][n]: n=l&15, k=(l>>4)*4+j   (lane loads 4 contiguous dims of W row n)
//   D[m][n]: n=l&15, m=(l>>4)*4+r   (m89-verified C/D mapping)
// Each wave: 16 B-frags (W^T, held in 32 VGPRs), 16-node tiles, 16 MFMA/tile,
// fp32 acc init = bias. fp16 input rounding ~1e-3 abs -- below the bf16 store
// quantization that is already in the accepted output.
//
// Kp16 word layout (PERMUTED vs old): word w = c + 16h of node n holds
//   lo16 = bf16(dim c+32h), hi16 = bf16(dim c+32h+16),  c=0..15, h=0..1.
// sort_agg compensates in its final store addressing only.
// ---------------------------------------------------------------------------
__global__ __launch_bounds__(256, 2) void proj_kernel(
    const float* __restrict__ qnodes, const float* __restrict__ kvnodes,
    const float* __restrict__ W, const float* __restrict__ pb,
    const float* __restrict__ aw, unsigned int* __restrict__ Kp16,
    float* __restrict__ sq, float* __restrict__ sk,
    int Nq, int Nk, int projBlocks) {
  const int t = threadIdx.x;
  __shared__ float pt0[256];
  __shared__ float pt1[256];
  __shared__ __align__(16) float us[64];
  __shared__ __align__(16) float uk[64];
  __shared__ float cq_s, ck_s;
  const int lane = t & 63;
  const int waveId = blockIdx.x * 4 + (t >> 6);
  const int nWaves = projBlocks * 4;

  // fold: us = W^T aw_q, uk = W^T aw_k (read W direct from global, coalesced)
  {
    const int pd = t & 63, og = t >> 6;
    float s0 = 0.f, s1 = 0.f;
#pragma unroll
    for (int oo = 0; oo < 16; ++oo) {
      const int o = og * 16 + oo;
      const float wv = W[o * 64 + pd];
      s0 = fmaf(aw[o], wv, s0);
      s1 = fmaf(aw[64 + o], wv, s1);
    }
    pt0[t] = s0;
    pt1[t] = s1;
  }
  __syncthreads();
  if (t < 64) {
    us[t] = (pt0[t] + pt0[t + 64]) + (pt0[t + 128] + pt0[t + 192]);
    uk[t] = (pt1[t] + pt1[t + 64]) + (pt1[t + 128] + pt1[t + 192]);
    if (t == 0) {
      float c0 = 0.f, c1 = 0.f;
      for (int o = 0; o < 64; ++o) {
        c0 = fmaf(aw[o], pb[o], c0);
        c1 = fmaf(aw[64 + o], pb[o], c1);
      }
      cq_s = c0;
      ck_s = c1;
    }
  }
  __syncthreads();

  // q-side gemv: sq[n] = qnodes[n,:].us + cq (4 nodes per wave-iter)
  {
    const int sub = lane & 15, ng = lane >> 4;
    const float4 uv = ((const float4*)us)[sub];
    const float c = cq_s;
    for (int base = waveId * 4; base < Nq; base += nWaves * 4) {
      const int n = base + ng;
      float s = 0.f;
      if (n < Nq) {
        const float4 x = *(const float4*)(qnodes + (size_t)n * 64 + sub * 4);
        s = x.x * uv.x + x.y * uv.y + x.z * uv.z + x.w * uv.w;
      }
#pragma unroll
      for (int off = 1; off <= 8; off <<= 1) s += __shfl_xor(s, off, 64);
      if (sub == 0 && n < Nq) sq[n] = s + c;
    }
  }

  // k-side folded gemv: sk[n] = kvnodes[n,:].uk + ck
  {
    const int sub = lane & 15, ng = lane >> 4;
    const float4 uv = ((const float4*)uk)[sub];
    const float c = ck_s;
    for (int base = waveId * 4; base < Nk; base += nWaves * 4) {
      const int n = base + ng;
      float s = 0.f;
      if (n < Nk) {
        const float4 x = *(const float4*)(kvnodes + (size_t)n * 64 + sub * 4);
        s = x.x * uv.x + x.y * uv.y + x.z * uv.z + x.w * uv.w;
      }
#pragma unroll
      for (int off = 1; off <= 8; off <<= 1) s += __shfl_xor(s, off, 64);
      if (sub == 0 && n < Nk) sk[n] = s + c;
    }
  }

  // ---- MFMA kv projection ----
  const int c = lane & 15, g = lane >> 4;

  // B-frags (W^T) + bias, persistent across tiles
  half4_t Bf[4][4];  // [nt][ks] -- compile-time indexed only (full unroll)
  float pbv[4];
#pragma unroll
  for (int nt = 0; nt < 4; ++nt) {
    pbv[nt] = pb[nt * 16 + c];
#pragma unroll
    for (int ks = 0; ks < 4; ++ks) {
      const float4 wv =
          *(const float4*)(W + (size_t)(nt * 16 + c) * 64 + ks * 16 + g * 4);
      half4_t h;
      h[0] = (_Float16)wv.x;
      h[1] = (_Float16)wv.y;
      h[2] = (_Float16)wv.z;
      h[3] = (_Float16)wv.w;
      Bf[nt][ks] = h;
    }
  }

  const int ntiles = (Nk + 15) >> 4;
  for (int tile = waveId; tile < ntiles; tile += nWaves) {
    const int n0 = tile << 4;
    const int arow = n0 + c;
    const bool aok = arow < Nk;
    const float* xr = kvnodes + (size_t)arow * 64 + g * 4;

    half4_t Af[4];
#pragma unroll
    for (int ks = 0; ks < 4; ++ks) {
      const float4 xv =
          aok ? *(const float4*)(xr + ks * 16) : make_float4(0.f, 0.f, 0.f, 0.f);
      half4_t h;
      h[0] = (_Float16)xv.x;
      h[1] = (_Float16)xv.y;
      h[2] = (_Float16)xv.z;
      h[3] = (_Float16)xv.w;
      Af[ks] = h;
    }

    f32x4 acc0 = {pbv[0], pbv[0], pbv[0], pbv[0]};
    f32x4 acc1 = {pbv[1], pbv[1], pbv[1], pbv[1]};
    f32x4 acc2 = {pbv[2], pbv[2], pbv[2], pbv[2]};
    f32x4 acc3 = {pbv[3], pbv[3], pbv[3], pbv[3]};
#pragma unroll
    for (int ks = 0; ks < 4; ++ks) {
      acc0 = __builtin_amdgcn_mfma_f32_16x16x16f16(Af[ks], Bf[0][ks], acc0, 0, 0, 0);
      acc1 = __builtin_amdgcn_mfma_f32_16x16x16f16(Af[ks], Bf[1][ks], acc1, 0, 0, 0);
      acc2 = __builtin_amdgcn_mfma_f32_16x16x16f16(Af[ks], Bf[2][ks], acc2, 0, 0, 0);
      acc3 = __builtin_amdgcn_mfma_f32_16x16x16f16(Af[ks], Bf[3][ks], acc3, 0, 0, 0);
    }

    // epilogue: lane holds D[node n0+g*4+r][o = nt*16 + c] = accN[r]
#pragma unroll
    for (int r = 0; r < 4; ++r) {
      const int node = n0 + g * 4 + r;
      if (node < Nk) {
        const unsigned int u0 =
            ((unsigned int)f2bf(acc1[r]) << 16) | f2bf(acc0[r]);  // dims c, c+16
        const unsigned int u1 =
            ((unsigned int)f2bf(acc3[r]) << 16) | f2bf(acc2[r]);  // dims c+32, c+48
        unsigned int* kp = Kp16 + (size_t)node * 32;
        kp[c] = u0;
        kp[16 + c] = u1;
      }
    }
  }
}

// ---------------------------------------------------------------------------
// bucket_scan: exclusive scan of gcnt[0..NB) -> gbase, gcursor. NB <= 1024.
// ---------------------------------------------------------------------------
__global__ __launch_bounds__(1024) void bucket_scan(
    const int* __restrict__ gcnt, int* __restrict__ gbase,
    int* __restrict__ gcursor, int NB) {
  __shared__ int wso[16];
  const int t = threadIdx.x, lane = t & 63, wv = t >> 6;
  const int v = (t < NB) ? gcnt[t] : 0;
  int x = v;
#pragma unroll
  for (int off = 1; off < 64; off <<= 1) {
    const int y = __shfl_up(x, off, 64);
    if (lane >= off) x += y;
  }
  if (lane == 63) wso[wv] = x;
  __syncthreads();
  int woff = 0;
  for (int w = 0; w < wv; ++w) woff += wso[w];
  const int excl = woff + x - v;
  if (t < NB) { gbase[t] = excl; gcursor[t] = excl; }
}

// ---------------------------------------------------------------------------
// bin_kernel: 1024 threads, 16384 edges/block: coalesced int4 reads into
// registers, LDS per-bucket count, ONE reservation atomic per bucket per
// block, (qi,ki) pairs written in ~168B contiguous runs.
// ---------------------------------------------------------------------------
__global__ __launch_bounds__(1024) void bin_kernel(
    const int* __restrict__ eq, const int* __restrict__ ek,
    int* __restrict__ gcursor, int2* __restrict__ pairs, int E, int NB) {
  __shared__ int lcnt[NBMAX];
  __shared__ int lbase[NBMAX];
  const int t = threadIdx.x;
  for (int i = t; i < NBMAX; i += 1024) lcnt[i] = 0;
  __syncthreads();

  const int cbase = blockIdx.x * CHUNK;
  int4 qv[4], kv[4];
#pragma unroll
  for (int j = 0; j < 4; ++j) {
    const int e0 = cbase + (((j << 10) + t) << 2);
    if (e0 + 3 < E) {
      qv[j] = *(const int4*)(eq + e0);
      kv[j] = *(const int4*)(ek + e0);
    } else {
      int tq[4] = {-1, -1, -1, -1}, tk[4] = {0, 0, 0, 0};
      for (int r = 0; r < 4; ++r)
        if (e0 + r < E) { tq[r] = eq[e0 + r]; tk[r] = ek[e0 + r]; }
      qv[j] = make_int4(tq[0], tq[1], tq[2], tq[3]);
      kv[j] = make_int4(tk[0], tk[1], tk[2], tk[3]);
    }
    if (qv[j].x >= 0) atomicAdd(&lcnt[qv[j].x >> BSHIFT], 1);
    if (qv[j].y >= 0) atomicAdd(&lcnt[qv[j].y >> BSHIFT], 1);
    if (qv[j].z >= 0) atomicAdd(&lcnt[qv[j].z >> BSHIFT], 1);
    if (qv[j].w >= 0) atomicAdd(&lcnt[qv[j].w >> BSHIFT], 1);
  }
  __syncthreads();
  for (int i = t; i < NB; i += 1024) {
    lbase[i] = lcnt[i] ? atomicAdd(&gcursor[i], lcnt[i]) : 0;
    lcnt[i] = 0;
  }
  __syncthreads();
#pragma unroll
  for (int j = 0; j < 4; ++j) {
    const int qs[4] = {qv[j].x, qv[j].y, qv[j].z, qv[j].w};
    const int ks[4] = {kv[j].x, kv[j].y, kv[j].z, kv[j].w};
#pragma unroll
    for (int r = 0; r < 4; ++r) {
      if (qs[r] >= 0) {
        const int b = qs[r] >> BSHIFT;
        pairs[lbase[b] + atomicAdd(&lcnt[b], 1)] = make_int2(qs[r], ks[r]);
      }
    }
  }
}

// ---------------------------------------------------------------------------
// sort_agg_kernel: one 512-thr block per 128-qi bucket.
// Phase A: register-cache the bucket's pairs, LDS counting-sort ki -> kibuf.
// Phase B (TRANSPOSED): lane = (node-sub ng 0..7, dim-group dg 0..7).
// Kp16 word layout (from MFMA proj): word w = c + 16h of node k holds
// (lo,hi) = bf16 dims (c+32h, c+32h+16). The uint4 read at words 4dg..4dg+3
// therefore unpacks to dims {obase..obase+3} (lo's) and {obase+16..+19}
// (hi's) with obase = (dg&3)*4 + (dg>>2)*32 -- only the final store
// addressing changes vs the old layout; the fma loop is identical.
// ---------------------------------------------------------------------------
__global__ __launch_bounds__(512, 6) void sort_agg_kernel(
    const int2* __restrict__ pairs, const int* __restrict__ gcnt,
    const int* __restrict__ gbase, const float* __restrict__ sq,
    const float* __restrict__ sk, const float* __restrict__ ab,
    const unsigned int* __restrict__ Kp16, float* __restrict__ out,
    int Nq) {
  __shared__ int lcnt[BRANGE];
  __shared__ int lcur[BRANGE];
  __shared__ int lstart[BRANGE + 1];
  __shared__ int kibuf[KBUF_CAP];
  __shared__ int wso2[2];

  const int t = threadIdx.x;
  const int b = blockIdx.x;
  const int qlo = b << BSHIFT;
  int n = gcnt[b];
  if (n > KBUF_CAP) n = KBUF_CAP;  // statistically never; OOB guard
  const int base = gbase[b];

  if (t < BRANGE) lcnt[t] = 0;
  __syncthreads();

  // cache this thread's pairs (<= 6 at KBUF_CAP 3072)
  int2 pv[6];
  int np = 0;
#pragma unroll
  for (int r = 0; r < 6; ++r) {
    const int i = t + (r << 9);
    if (i < n) { pv[r] = pairs[base + i]; ++np; }
  }
#pragma unroll
  for (int r = 0; r < 6; ++r)
    if (r < np) atomicAdd(&lcnt[pv[r].x - qlo], 1);
  __syncthreads();

  // exclusive scan of lcnt[0..127] (first 2 waves)
  const int lane = t & 63, wv = t >> 6;
  int v = 0, x = 0;
  if (t < BRANGE) {
    v = lcnt[t];
    x = v;
#pragma unroll
    for (int off = 1; off < 64; off <<= 1) {
      const int y = __shfl_up(x, off, 64);
      if (lane >= off) x += y;
    }
    if (lane == 63) wso2[wv] = x;
  }
  __syncthreads();
  if (t < BRANGE) {
    const int excl = ((wv == 1) ? wso2[0] : 0) + x - v;
    lstart[t] = excl;
    lcur[t] = excl;
    if (t == BRANGE - 1) lstart[BRANGE] = excl + v;
  }
  __syncthreads();

  // scatter ki into kibuf (sorted by local qi)
#pragma unroll
  for (int r = 0; r < 6; ++r)
    if (r < np) kibuf[atomicAdd(&lcur[pv[r].x - qlo], 1)] = pv[r].y;
  __syncthreads();

  // Phase B: transposed aggregation. 8 waves x 8 nodes = 64 nodes per pass.
  const int ng = lane >> 3, dg = lane & 7;
  const float abv = ab[0];
#pragma unroll
  for (int pass = 0; pass < 2; ++pass) {
    const int l = (pass << 6) + (wv << 3) + ng;
    const int node = qlo + l;
    const bool act = node < Nq;
    const int s = act ? lstart[l] : 0;
    const int e = act ? lstart[l + 1] : 0;
    const float sqn = act ? sq[node] + abv : 0.f;

    float acc[8] = {0.f, 0.f, 0.f, 0.f, 0.f, 0.f, 0.f, 0.f};
    float wsum = 0.f;
    int j = s;
    for (; j + 1 < e; j += 2) {
      const int k1 = kibuf[j];
      const int k2 = kibuf[j + 1];
      float x1 = sqn + sk[k1];
      float x2 = sqn + sk[k2];
      x1 = x1 > 0.f ? x1 : ALPHA_LEAKY * x1;
      x2 = x2 > 0.f ? x2 : ALPHA_LEAKY * x2;
      const float w1 = __expf(x1);
      const float w2 = __expf(x2);
      const uint4 u1 = *(const uint4*)(Kp16 + (size_t)k1 * 32 + (dg << 2));
      const uint4 u2 = *(const uint4*)(Kp16 + (size_t)k2 * 32 + (dg << 2));
      acc[0] = fmaf(w1, __uint_as_float(u1.x << 16), acc[0]);
      acc[1] = fmaf(w1, __uint_as_float(u1.x & 0xffff0000u), acc[1]);
      acc[2] = fmaf(w1, __uint_as_float(u1.y << 16), acc[2]);
      acc[3] = fmaf(w1, __uint_as_float(u1.y & 0xffff0000u), acc[3]);
      acc[4] = fmaf(w1, __uint_as_float(u1.z << 16), acc[4]);
      acc[5] = fmaf(w1, __uint_as_float(u1.z & 0xffff0000u), acc[5]);
      acc[6] = fmaf(w1, __uint_as_float(u1.w << 16), acc[6]);
      acc[7] = fmaf(w1, __uint_as_float(u1.w & 0xffff0000u), acc[7]);
      acc[0] = fmaf(w2, __uint_as_float(u2.x << 16), acc[0]);
      acc[1] = fmaf(w2, __uint_as_float(u2.x & 0xffff0000u), acc[1]);
      acc[2] = fmaf(w2, __uint_as_float(u2.y << 16), acc[2]);
      acc[3] = fmaf(w2, __uint_as_float(u2.y & 0xffff0000u), acc[3]);
      acc[4] = fmaf(w2, __uint_as_float(u2.z << 16), acc[4]);
      acc[5] = fmaf(w2, __uint_as_float(u2.z & 0xffff0000u), acc[5]);
      acc[6] = fmaf(w2, __uint_as_float(u2.w << 16), acc[6]);
      acc[7] = fmaf(w2, __uint_as_float(u2.w & 0xffff0000u), acc[7]);
      wsum += w1 + w2;
    }
    if (j < e) {
      const int k1 = kibuf[j];
      float x1 = sqn + sk[k1];
      x1 = x1 > 0.f ? x1 : ALPHA_LEAKY * x1;
      const float w1 = __expf(x1);
      const uint4 u1 = *(const uint4*)(Kp16 + (size_t)k1 * 32 + (dg << 2));
      acc[0] = fmaf(w1, __uint_as_float(u1.x << 16), acc[0]);
      acc[1] = fmaf(w1, __uint_as_float(u1.x & 0xffff0000u), acc[1]);
      acc[2] = fmaf(w1, __uint_as_float(u1.y << 16), acc[2]);
      acc[3] = fmaf(w1, __uint_as_float(u1.y & 0xffff0000u), acc[3]);
      acc[4] = fmaf(w1, __uint_as_float(u1.z << 16), acc[4]);
      acc[5] = fmaf(w1, __uint_as_float(u1.z & 0xffff0000u), acc[5]);
      acc[6] = fmaf(w1, __uint_as_float(u1.w << 16), acc[6]);
      acc[7] = fmaf(w1, __uint_as_float(u1.w & 0xffff0000u), acc[7]);
      wsum += w1;
    }
    if (act) {
      const float inv = 1.0f / (wsum + EPS_F);
      const int obase = ((dg & 3) << 2) + ((dg >> 2) << 5);
      float4 r0 = {acc[0] * inv, acc[2] * inv, acc[4] * inv, acc[6] * inv};
      float4 r1 = {acc[1] * inv, acc[3] * inv, acc[5] * inv, acc[7] * inv};
      float* o = out + (size_t)node * 64 + obase;
      *(float4*)o = r0;
      *(float4*)(o + 16) = r1;
    }
  }
}

extern "C" void kernel_launch(void* const* d_in, const int* in_sizes, int n_in,
                              void* d_out, int out_size, void* d_ws, size_t ws_size,
                              hipStream_t stream) {
  const float* qnodes = (const float*)d_in[0];   // (Nq, 64) f32
  const float* kvnodes = (const float*)d_in[1];  // (Nk, 64) f32
  const int* ei = (const int*)d_in[2];           // (2, E) int32
  const float* W = (const float*)d_in[3];        // (64, 64)
  const float* pb = (const float*)d_in[4];       // (64,)
  const float* aw = (const float*)d_in[5];       // (1, 128): [wq | wk]
  const float* ab = (const float*)d_in[6];       // (1,)

  const int Nq = in_sizes[0] / 64;
  const int Nk = in_sizes[1] / 64;
  const int E = in_sizes[2] / 2;
  const int NB = (Nq + BRANGE - 1) >> BSHIFT;    // 782 at Nq=100000

  const int* eq = ei;
  const int* ek = ei + E;

  // --- workspace layout ---
  char* ws = (char*)d_ws;
  int2* pairs = (int2*)ws;                              // E int2
  unsigned int* Kp16 = (unsigned int*)(pairs + E);      // Nk*32 words
  float* sq = (float*)(Kp16 + (size_t)Nk * 32);         // Nq
  float* sk = sq + Nq;                                  // Nk
  int* gcnt = (int*)(sk + Nk);                          // NBMAX
  int* gbase = gcnt + NBMAX;                            // NBMAX
  int* gcursor = gbase + NBMAX;                         // NBMAX

  hipMemsetAsync(gcnt, 0, NBMAX * sizeof(int), stream);

  // --- hist and proj as separate dispatches ---
  hist_kernel<<<HIST_BLOCKS, 256, 0, stream>>>(eq, gcnt, E, NB);

  const int projBlocks = 768;
  proj_kernel<<<projBlocks, 256, 0, stream>>>(qnodes, kvnodes, W, pb, aw,
                                              Kp16, sq, sk, Nq, Nk,
                                              projBlocks);

  // --- scan + binning ---
  bucket_scan<<<1, 1024, 0, stream>>>(gcnt, gbase, gcursor, NB);
  bin_kernel<<<(E + CHUNK - 1) / CHUNK, 1024, 0, stream>>>(eq, ek, gcursor,
                                                           pairs, E, NB);

  // --- fused bucket sort + transposed aggregation ---
  sort_agg_kernel<<<NB, 512, 0, stream>>>(pairs, gcnt, gbase, sq, sk, ab,
                                          Kp16, (float*)d_out, Nq);
}

// Round 6
// 193.309 us; speedup vs baseline: 1.1733x; 1.0027x over previous
//
#include <hip/hip_runtime.h>

#define ALPHA_LEAKY 0.2f
#define EPS_F 1e-10f

#define BSHIFT 7            // bucket = 128 qi
#define BRANGE 128
#define NBMAX 1024          // max buckets (Nq <= 131072)
#define CHUNK 16384         // edges per bin_kernel block
#define KBUF_CAP 3072       // bucket LDS capacity (avg 2048, +22 sigma)
#define HIST_BLOCKS 512

using half4_t = __attribute__((ext_vector_type(4))) _Float16;
using f32x4 = __attribute__((ext_vector_type(4))) float;

// RNE float -> bf16
__device__ __forceinline__ unsigned short f2bf(float x) {
  unsigned int u = __float_as_uint(x);
  return (unsigned short)((u + 0x7fffu + ((u >> 16) & 1u)) >> 16);
}

// ---------------------------------------------------------------------------
// hist_kernel: LDS histogram of qi>>BSHIFT -> gcnt.
// ---------------------------------------------------------------------------
__global__ __launch_bounds__(256) void hist_kernel(
    const int* __restrict__ eq, int* __restrict__ gcnt, int E, int NB) {
  const int t = threadIdx.x;
  __shared__ int lcnt[NBMAX];
  for (int i = t; i < NBMAX; i += 256) lcnt[i] = 0;
  __syncthreads();
  const int n4 = E >> 2;
  for (int i = blockIdx.x * 256 + t; i < n4; i += HIST_BLOCKS * 256) {
    const int4 q = ((const int4*)eq)[i];
    atomicAdd(&lcnt[q.x >> BSHIFT], 1);
    atomicAdd(&lcnt[q.y >> BSHIFT], 1);
    atomicAdd(&lcnt[q.z >> BSHIFT], 1);
    atomicAdd(&lcnt[q.w >> BSHIFT], 1);
  }
  if (blockIdx.x == 0 && t < (E & 3))
    atomicAdd(&lcnt[eq[(n4 << 2) + t] >> BSHIFT], 1);
  __syncthreads();
  for (int i = t; i < NB; i += 256)
    if (lcnt[i]) atomicAdd(&gcnt[i], lcnt[i]);
}

// ---------------------------------------------------------------------------
// proj_kernel v2: MFMA projection (validated round 5: proj fell out of the
// top-5, absmax unchanged). See round-4 comment for fragment layout.
// Kp16 word layout (PERMUTED): word w = c + 16h of node n holds
//   lo16 = bf16(dim c+32h), hi16 = bf16(dim c+32h+16),  c=0..15, h=0..1.
// ---------------------------------------------------------------------------
__global__ __launch_bounds__(256, 2) void proj_kernel(
    const float* __restrict__ qnodes, const float* __restrict__ kvnodes,
    const float* __restrict__ W, const float* __restrict__ pb,
    const float* __restrict__ aw, unsigned int* __restrict__ Kp16,
    float* __restrict__ sq, float* __restrict__ sk,
    int Nq, int Nk, int projBlocks) {
  const int t = threadIdx.x;
  __shared__ float pt0[256];
  __shared__ float pt1[256];
  __shared__ __align__(16) float us[64];
  __shared__ __align__(16) float uk[64];
  __shared__ float cq_s, ck_s;
  const int lane = t & 63;
  const int waveId = blockIdx.x * 4 + (t >> 6);
  const int nWaves = projBlocks * 4;

  // fold: us = W^T aw_q, uk = W^T aw_k (read W direct from global, coalesced)
  {
    const int pd = t & 63, og = t >> 6;
    float s0 = 0.f, s1 = 0.f;
#pragma unroll
    for (int oo = 0; oo < 16; ++oo) {
      const int o = og * 16 + oo;
      const float wv = W[o * 64 + pd];
      s0 = fmaf(aw[o], wv, s0);
      s1 = fmaf(aw[64 + o], wv, s1);
    }
    pt0[t] = s0;
    pt1[t] = s1;
  }
  __syncthreads();
  if (t < 64) {
    us[t] = (pt0[t] + pt0[t + 64]) + (pt0[t + 128] + pt0[t + 192]);
    uk[t] = (pt1[t] + pt1[t + 64]) + (pt1[t + 128] + pt1[t + 192]);
    if (t == 0) {
      float c0 = 0.f, c1 = 0.f;
      for (int o = 0; o < 64; ++o) {
        c0 = fmaf(aw[o], pb[o], c0);
        c1 = fmaf(aw[64 + o], pb[o], c1);
      }
      cq_s = c0;
      ck_s = c1;
    }
  }
  __syncthreads();

  // q-side gemv: sq[n] = qnodes[n,:].us + cq (4 nodes per wave-iter)
  {
    const int sub = lane & 15, ng = lane >> 4;
    const float4 uv = ((const float4*)us)[sub];
    const float c = cq_s;
    for (int base = waveId * 4; base < Nq; base += nWaves * 4) {
      const int n = base + ng;
      float s = 0.f;
      if (n < Nq) {
        const float4 x = *(const float4*)(qnodes + (size_t)n * 64 + sub * 4);
        s = x.x * uv.x + x.y * uv.y + x.z * uv.z + x.w * uv.w;
      }
#pragma unroll
      for (int off = 1; off <= 8; off <<= 1) s += __shfl_xor(s, off, 64);
      if (sub == 0 && n < Nq) sq[n] = s + c;
    }
  }

  // k-side folded gemv: sk[n] = kvnodes[n,:].uk + ck
  {
    const int sub = lane & 15, ng = lane >> 4;
    const float4 uv = ((const float4*)uk)[sub];
    const float c = ck_s;
    for (int base = waveId * 4; base < Nk; base += nWaves * 4) {
      const int n = base + ng;
      float s = 0.f;
      if (n < Nk) {
        const float4 x = *(const float4*)(kvnodes + (size_t)n * 64 + sub * 4);
        s = x.x * uv.x + x.y * uv.y + x.z * uv.z + x.w * uv.w;
      }
#pragma unroll
      for (int off = 1; off <= 8; off <<= 1) s += __shfl_xor(s, off, 64);
      if (sub == 0 && n < Nk) sk[n] = s + c;
    }
  }

  // ---- MFMA kv projection ----
  const int c = lane & 15, g = lane >> 4;

  // B-frags (W^T) + bias, persistent across tiles
  half4_t Bf[4][4];  // [nt][ks] -- compile-time indexed only (full unroll)
  float pbv[4];
#pragma unroll
  for (int nt = 0; nt < 4; ++nt) {
    pbv[nt] = pb[nt * 16 + c];
#pragma unroll
    for (int ks = 0; ks < 4; ++ks) {
      const float4 wv =
          *(const float4*)(W + (size_t)(nt * 16 + c) * 64 + ks * 16 + g * 4);
      half4_t h;
      h[0] = (_Float16)wv.x;
      h[1] = (_Float16)wv.y;
      h[2] = (_Float16)wv.z;
      h[3] = (_Float16)wv.w;
      Bf[nt][ks] = h;
    }
  }

  const int ntiles = (Nk + 15) >> 4;
  for (int tile = waveId; tile < ntiles; tile += nWaves) {
    const int n0 = tile << 4;
    const int arow = n0 + c;
    const bool aok = arow < Nk;
    const float* xr = kvnodes + (size_t)arow * 64 + g * 4;

    half4_t Af[4];
#pragma unroll
    for (int ks = 0; ks < 4; ++ks) {
      const float4 xv =
          aok ? *(const float4*)(xr + ks * 16) : make_float4(0.f, 0.f, 0.f, 0.f);
      half4_t h;
      h[0] = (_Float16)xv.x;
      h[1] = (_Float16)xv.y;
      h[2] = (_Float16)xv.z;
      h[3] = (_Float16)xv.w;
      Af[ks] = h;
    }

    f32x4 acc0 = {pbv[0], pbv[0], pbv[0], pbv[0]};
    f32x4 acc1 = {pbv[1], pbv[1], pbv[1], pbv[1]};
    f32x4 acc2 = {pbv[2], pbv[2], pbv[2], pbv[2]};
    f32x4 acc3 = {pbv[3], pbv[3], pbv[3], pbv[3]};
#pragma unroll
    for (int ks = 0; ks < 4; ++ks) {
      acc0 = __builtin_amdgcn_mfma_f32_16x16x16f16(Af[ks], Bf[0][ks], acc0, 0, 0, 0);
      acc1 = __builtin_amdgcn_mfma_f32_16x16x16f16(Af[ks], Bf[1][ks], acc1, 0, 0, 0);
      acc2 = __builtin_amdgcn_mfma_f32_16x16x16f16(Af[ks], Bf[2][ks], acc2, 0, 0, 0);
      acc3 = __builtin_amdgcn_mfma_f32_16x16x16f16(Af[ks], Bf[3][ks], acc3, 0, 0, 0);
    }

    // epilogue: lane holds D[node n0+g*4+r][o = nt*16 + c] = accN[r]
#pragma unroll
    for (int r = 0; r < 4; ++r) {
      const int node = n0 + g * 4 + r;
      if (node < Nk) {
        const unsigned int u0 =
            ((unsigned int)f2bf(acc1[r]) << 16) | f2bf(acc0[r]);  // dims c, c+16
        const unsigned int u1 =
            ((unsigned int)f2bf(acc3[r]) << 16) | f2bf(acc2[r]);  // dims c+32, c+48
        unsigned int* kp = Kp16 + (size_t)node * 32;
        kp[c] = u0;
        kp[16 + c] = u1;
      }
    }
  }
}

// ---------------------------------------------------------------------------
// bucket_scan: exclusive scan of gcnt[0..NB) -> gbase, gcursor. NB <= 1024.
// ---------------------------------------------------------------------------
__global__ __launch_bounds__(1024) void bucket_scan(
    const int* __restrict__ gcnt, int* __restrict__ gbase,
    int* __restrict__ gcursor, int NB) {
  __shared__ int wso[16];
  const int t = threadIdx.x, lane = t & 63, wv = t >> 6;
  const int v = (t < NB) ? gcnt[t] : 0;
  int x = v;
#pragma unroll
  for (int off = 1; off < 64; off <<= 1) {
    const int y = __shfl_up(x, off, 64);
    if (lane >= off) x += y;
  }
  if (lane == 63) wso[wv] = x;
  __syncthreads();
  int woff = 0;
  for (int w = 0; w < wv; ++w) woff += wso[w];
  const int excl = woff + x - v;
  if (t < NB) { gbase[t] = excl; gcursor[t] = excl; }
}

// ---------------------------------------------------------------------------
// bin_kernel: 1024 threads, 16384 edges/block: coalesced int4 reads into
// registers, LDS per-bucket count, ONE reservation atomic per bucket per
// block, (qi,ki) pairs written in ~168B contiguous runs.
// ---------------------------------------------------------------------------
__global__ __launch_bounds__(1024) void bin_kernel(
    const int* __restrict__ eq, const int* __restrict__ ek,
    int* __restrict__ gcursor, int2* __restrict__ pairs, int E, int NB) {
  __shared__ int lcnt[NBMAX];
  __shared__ int lbase[NBMAX];
  const int t = threadIdx.x;
  for (int i = t; i < NBMAX; i += 1024) lcnt[i] = 0;
  __syncthreads();

  const int cbase = blockIdx.x * CHUNK;
  int4 qv[4], kv[4];
#pragma unroll
  for (int j = 0; j < 4; ++j) {
    const int e0 = cbase + (((j << 10) + t) << 2);
    if (e0 + 3 < E) {
      qv[j] = *(const int4*)(eq + e0);
      kv[j] = *(const int4*)(ek + e0);
    } else {
      int tq[4] = {-1, -1, -1, -1}, tk[4] = {0, 0, 0, 0};
      for (int r = 0; r < 4; ++r)
        if (e0 + r < E) { tq[r] = eq[e0 + r]; tk[r] = ek[e0 + r]; }
      qv[j] = make_int4(tq[0], tq[1], tq[2], tq[3]);
      kv[j] = make_int4(tk[0], tk[1], tk[2], tk[3]);
    }
    if (qv[j].x >= 0) atomicAdd(&lcnt[qv[j].x >> BSHIFT], 1);
    if (qv[j].y >= 0) atomicAdd(&lcnt[qv[j].y >> BSHIFT], 1);
    if (qv[j].z >= 0) atomicAdd(&lcnt[qv[j].z >> BSHIFT], 1);
    if (qv[j].w >= 0) atomicAdd(&lcnt[qv[j].w >> BSHIFT], 1);
  }
  __syncthreads();
  for (int i = t; i < NB; i += 1024) {
    lbase[i] = lcnt[i] ? atomicAdd(&gcursor[i], lcnt[i]) : 0;
    lcnt[i] = 0;
  }
  __syncthreads();
#pragma unroll
  for (int j = 0; j < 4; ++j) {
    const int qs[4] = {qv[j].x, qv[j].y, qv[j].z, qv[j].w};
    const int ks[4] = {kv[j].x, kv[j].y, kv[j].z, kv[j].w};
#pragma unroll
    for (int r = 0; r < 4; ++r) {
      if (qs[r] >= 0) {
        const int b = qs[r] >> BSHIFT;
        pairs[lbase[b] + atomicAdd(&lcnt[b], 1)] = make_int2(qs[r], ks[r]);
      }
    }
  }
}

// ---------------------------------------------------------------------------
// sort_agg_kernel: one 512-thr block per 128-qi bucket.
// Phase A: register-cache the bucket's pairs, LDS counting-sort ki -> kibuf.
// Phase B (TRANSPOSED + BATCH-4): round-5 counters showed latency-bound
// (VALUBusy 30%, HBM 32%, dur 43.6us vs 17us traffic floor): the per-edge
// chain kibuf(LDS ~120cy) -> sk/Kp16 gather (~200-500cy) -> fma covered only
// ~44cy of issue with 6 waves/SIMD. Batch 4 edges with CLAMPED indices:
// 4 independent kibuf reads (one lgkm wait), 8 independent VMEM gathers (one
// vm wait), then compute. Clamped tail edges read a valid duplicate entry and
// get weight selected to exactly 0.f (select after exp -> no inf*0).
// Kp16 word layout (from MFMA proj): uint4 at words 4dg..4dg+3 unpacks to
// dims {obase..+3} (lo) and {obase+16..+19} (hi), obase=(dg&3)*4+(dg>>2)*32.
// ---------------------------------------------------------------------------
__global__ __launch_bounds__(512, 6) void sort_agg_kernel(
    const int2* __restrict__ pairs, const int* __restrict__ gcnt,
    const int* __restrict__ gbase, const float* __restrict__ sq,
    const float* __restrict__ sk, const float* __restrict__ ab,
    const unsigned int* __restrict__ Kp16, float* __restrict__ out,
    int Nq) {
  __shared__ int lcnt[BRANGE];
  __shared__ int lcur[BRANGE];
  __shared__ int lstart[BRANGE + 1];
  __shared__ int kibuf[KBUF_CAP];
  __shared__ int wso2[2];

  const int t = threadIdx.x;
  const int b = blockIdx.x;
  const int qlo = b << BSHIFT;
  int n = gcnt[b];
  if (n > KBUF_CAP) n = KBUF_CAP;  // statistically never; OOB guard
  const int base = gbase[b];

  if (t < BRANGE) lcnt[t] = 0;
  __syncthreads();

  // cache this thread's pairs (<= 6 at KBUF_CAP 3072)
  int2 pv[6];
  int np = 0;
#pragma unroll
  for (int r = 0; r < 6; ++r) {
    const int i = t + (r << 9);
    if (i < n) { pv[r] = pairs[base + i]; ++np; }
  }
#pragma unroll
  for (int r = 0; r < 6; ++r)
    if (r < np) atomicAdd(&lcnt[pv[r].x - qlo], 1);
  __syncthreads();

  // exclusive scan of lcnt[0..127] (first 2 waves)
  const int lane = t & 63, wv = t >> 6;
  int v = 0, x = 0;
  if (t < BRANGE) {
    v = lcnt[t];
    x = v;
#pragma unroll
    for (int off = 1; off < 64; off <<= 1) {
      const int y = __shfl_up(x, off, 64);
      if (lane >= off) x += y;
    }
    if (lane == 63) wso2[wv] = x;
  }
  __syncthreads();
  if (t < BRANGE) {
    const int excl = ((wv == 1) ? wso2[0] : 0) + x - v;
    lstart[t] = excl;
    lcur[t] = excl;
    if (t == BRANGE - 1) lstart[BRANGE] = excl + v;
  }
  __syncthreads();

  // scatter ki into kibuf (sorted by local qi)
#pragma unroll
  for (int r = 0; r < 6; ++r)
    if (r < np) kibuf[atomicAdd(&lcur[pv[r].x - qlo], 1)] = pv[r].y;
  __syncthreads();

  // Phase B: transposed aggregation. 8 waves x 8 nodes = 64 nodes per pass.
  const int ng = lane >> 3, dg = lane & 7;
  const float abv = ab[0];
#pragma unroll
  for (int pass = 0; pass < 2; ++pass) {
    const int l = (pass << 6) + (wv << 3) + ng;
    const int node = qlo + l;
    const bool act = node < Nq;
    const int s = act ? lstart[l] : 0;
    const int e = act ? lstart[l + 1] : 0;
    const float sqn = act ? sq[node] + abv : 0.f;

    float acc[8] = {0.f, 0.f, 0.f, 0.f, 0.f, 0.f, 0.f, 0.f};
    float wsum = 0.f;
    const int jm = e - 1;
#pragma unroll 1
    for (int j = s; j < e; j += 4) {
      // 4 independent LDS reads (single lgkm drain)
      const int ka = kibuf[j];
      const int kb = kibuf[min(j + 1, jm)];
      const int kc = kibuf[min(j + 2, jm)];
      const int kd = kibuf[min(j + 3, jm)];
      // 8 independent VMEM gathers (single vm drain)
      const float ea = sk[ka];
      const float eb = sk[kb];
      const float ec = sk[kc];
      const float ed = sk[kd];
      const uint4 ua = *(const uint4*)(Kp16 + (size_t)ka * 32 + (dg << 2));
      const uint4 ub = *(const uint4*)(Kp16 + (size_t)kb * 32 + (dg << 2));
      const uint4 uc = *(const uint4*)(Kp16 + (size_t)kc * 32 + (dg << 2));
      const uint4 ud = *(const uint4*)(Kp16 + (size_t)kd * 32 + (dg << 2));

      float xa = sqn + ea; xa = xa > 0.f ? xa : ALPHA_LEAKY * xa;
      float xb = sqn + eb; xb = xb > 0.f ? xb : ALPHA_LEAKY * xb;
      float xc = sqn + ec; xc = xc > 0.f ? xc : ALPHA_LEAKY * xc;
      float xd = sqn + ed; xd = xd > 0.f ? xd : ALPHA_LEAKY * xd;
      const float wa = __expf(xa);
      const float wb = (j + 1 < e) ? __expf(xb) : 0.f;
      const float wc = (j + 2 < e) ? __expf(xc) : 0.f;
      const float wd = (j + 3 < e) ? __expf(xd) : 0.f;

#define ACC8(W, U)                                             \
  acc[0] = fmaf(W, __uint_as_float(U.x << 16), acc[0]);        \
  acc[1] = fmaf(W, __uint_as_float(U.x & 0xffff0000u), acc[1]);\
  acc[2] = fmaf(W, __uint_as_float(U.y << 16), acc[2]);        \
  acc[3] = fmaf(W, __uint_as_float(U.y & 0xffff0000u), acc[3]);\
  acc[4] = fmaf(W, __uint_as_float(U.z << 16), acc[4]);        \
  acc[5] = fmaf(W, __uint_as_float(U.z & 0xffff0000u), acc[5]);\
  acc[6] = fmaf(W, __uint_as_float(U.w << 16), acc[6]);        \
  acc[7] = fmaf(W, __uint_as_float(U.w & 0xffff0000u), acc[7]);
      ACC8(wa, ua)
      ACC8(wb, ub)
      ACC8(wc, uc)
      ACC8(wd, ud)
#undef ACC8
      wsum += (wa + wb) + (wc + wd);
    }

    if (act) {
      const float inv = 1.0f / (wsum + EPS_F);
      const int obase = ((dg & 3) << 2) + ((dg >> 2) << 5);
      float4 r0 = {acc[0] * inv, acc[2] * inv, acc[4] * inv, acc[6] * inv};
      float4 r1 = {acc[1] * inv, acc[3] * inv, acc[5] * inv, acc[7] * inv};
      float* o = out + (size_t)node * 64 + obase;
      *(float4*)o = r0;
      *(float4*)(o + 16) = r1;
    }
  }
}

extern "C" void kernel_launch(void* const* d_in, const int* in_sizes, int n_in,
                              void* d_out, int out_size, void* d_ws, size_t ws_size,
                              hipStream_t stream) {
  const float* qnodes = (const float*)d_in[0];   // (Nq, 64) f32
  const float* kvnodes = (const float*)d_in[1];  // (Nk, 64) f32
  const int* ei = (const int*)d_in[2];           // (2, E) int32
  const float* W = (const float*)d_in[3];        // (64, 64)
  const float* pb = (const float*)d_in[4];       // (64,)
  const float* aw = (const float*)d_in[5];       // (1, 128): [wq | wk]
  const float* ab = (const float*)d_in[6];       // (1,)

  const int Nq = in_sizes[0] / 64;
  const int Nk = in_sizes[1] / 64;
  const int E = in_sizes[2] / 2;
  const int NB = (Nq + BRANGE - 1) >> BSHIFT;    // 782 at Nq=100000

  const int* eq = ei;
  const int* ek = ei + E;

  // --- workspace layout ---
  char* ws = (char*)d_ws;
  int2* pairs = (int2*)ws;                              // E int2
  unsigned int* Kp16 = (unsigned int*)(pairs + E);      // Nk*32 words
  float* sq = (float*)(Kp16 + (size_t)Nk * 32);         // Nq
  float* sk = sq + Nq;                                  // Nk
  int* gcnt = (int*)(sk + Nk);                          // NBMAX
  int* gbase = gcnt + NBMAX;                            // NBMAX
  int* gcursor = gbase + NBMAX;                         // NBMAX

  hipMemsetAsync(gcnt, 0, NBMAX * sizeof(int), stream);

  // --- hist and proj as separate dispatches ---
  hist_kernel<<<HIST_BLOCKS, 256, 0, stream>>>(eq, gcnt, E, NB);

  const int projBlocks = 768;
  proj_kernel<<<projBlocks, 256, 0, stream>>>(qnodes, kvnodes, W, pb, aw,
                                              Kp16, sq, sk, Nq, Nk,
                                              projBlocks);

  // --- scan + binning ---
  bucket_scan<<<1, 1024, 0, stream>>>(gcnt, gbase, gcursor, NB);
  bin_kernel<<<(E + CHUNK - 1) / CHUNK, 1024, 0, stream>>>(eq, ek, gcursor,
                                                           pairs, E, NB);

  // --- fused bucket sort + transposed aggregation ---
  sort_agg_kernel<<<NB, 512, 0, stream>>>(pairs, gcnt, gbase, sq, sk, ab,
                                          Kp16, (float*)d_out, Nq);
}

// Round 7
// 179.690 us; speedup vs baseline: 1.2622x; 1.0758x over previous
//
#include <hip/hip_runtime.h>

#define ALPHA_LEAKY 0.2f
#define EPS_F 1e-10f

#define BSHIFT 7            // bucket = 128 qi
#define BRANGE 128
#define NBMAX 1024          // max buckets (Nq <= 131072)
#define CHUNK_F 4096        // edges per bin block (256 thr x 16 edges)
#define KBUF_CAP 3072       // per-bucket slot capacity (avg 2048, +22 sigma)

using half4_t = __attribute__((ext_vector_type(4))) _Float16;
using f32x4 = __attribute__((ext_vector_type(4))) float;

// RNE float -> bf16
__device__ __forceinline__ unsigned short f2bf(float x) {
  unsigned int u = __float_as_uint(x);
  return (unsigned short)((u + 0x7fffu + ((u >> 16) & 1u)) >> 16);
}

// ---------------------------------------------------------------------------
// bin_proj_kernel: two independent jobs fused into one dispatch so they fill
// the machine together (round-6 evidence: fully serial 6-dispatch pipeline;
// harness ws-poison fill is a fixed 41us tax, so remaining lever = pipeline
// structure).
//  blocks [0, binBlocks): edge binning into FIXED-CAPACITY bucket slots
//    pairs[b][0..KBUF_CAP). No histogram, no prefix scan: gcursor[b] is
//    reserved via atomicAdd and its final value IS the bucket count.
//    Capacity overflow (statistically never) drops the tail edge, matching
//    the old read-side clamp semantics.
//  blocks [binBlocks, +projBlocks): MFMA projection (validated round 5).
//    Kp16 word layout (PERMUTED): word w = c+16h of node n holds
//    lo16 = bf16(dim c+32h), hi16 = bf16(dim c+32h+16), c=0..15, h=0..1.
// ---------------------------------------------------------------------------
__global__ __launch_bounds__(256, 2) void bin_proj_kernel(
    const int* __restrict__ eq, const int* __restrict__ ek,
    int* __restrict__ gcursor, int2* __restrict__ pairs, int E, int NB,
    int binBlocks,
    const float* __restrict__ qnodes, const float* __restrict__ kvnodes,
    const float* __restrict__ W, const float* __restrict__ pb,
    const float* __restrict__ aw, unsigned int* __restrict__ Kp16,
    float* __restrict__ sq, float* __restrict__ sk,
    int Nq, int Nk, int projBlocks) {
  const int t = threadIdx.x;

  if (blockIdx.x < binBlocks) {
    // ---- binning ----
    __shared__ int lcnt[NBMAX];
    __shared__ int lbase[NBMAX];
    for (int i = t; i < NBMAX; i += 256) lcnt[i] = 0;
    __syncthreads();

    const int cbase = blockIdx.x * CHUNK_F;
    int4 qv[4], kv[4];
#pragma unroll
    for (int j = 0; j < 4; ++j) {
      const int e0 = cbase + (((j << 8) + t) << 2);
      if (e0 + 3 < E) {
        qv[j] = *(const int4*)(eq + e0);
        kv[j] = *(const int4*)(ek + e0);
      } else {
        int tq[4] = {-1, -1, -1, -1}, tk[4] = {0, 0, 0, 0};
        for (int r = 0; r < 4; ++r)
          if (e0 + r < E) { tq[r] = eq[e0 + r]; tk[r] = ek[e0 + r]; }
        qv[j] = make_int4(tq[0], tq[1], tq[2], tq[3]);
        kv[j] = make_int4(tk[0], tk[1], tk[2], tk[3]);
      }
      if (qv[j].x >= 0) atomicAdd(&lcnt[qv[j].x >> BSHIFT], 1);
      if (qv[j].y >= 0) atomicAdd(&lcnt[qv[j].y >> BSHIFT], 1);
      if (qv[j].z >= 0) atomicAdd(&lcnt[qv[j].z >> BSHIFT], 1);
      if (qv[j].w >= 0) atomicAdd(&lcnt[qv[j].w >> BSHIFT], 1);
    }
    __syncthreads();
    for (int i = t; i < NB; i += 256) {
      lbase[i] = lcnt[i] ? atomicAdd(&gcursor[i], lcnt[i]) : 0;
      lcnt[i] = 0;
    }
    __syncthreads();
#pragma unroll
    for (int j = 0; j < 4; ++j) {
      const int qs[4] = {qv[j].x, qv[j].y, qv[j].z, qv[j].w};
      const int ks[4] = {kv[j].x, kv[j].y, kv[j].z, kv[j].w};
#pragma unroll
      for (int r = 0; r < 4; ++r) {
        if (qs[r] >= 0) {
          const int b = qs[r] >> BSHIFT;
          const int idx = lbase[b] + atomicAdd(&lcnt[b], 1);
          if (idx < KBUF_CAP)
            pairs[(size_t)b * KBUF_CAP + idx] = make_int2(qs[r], ks[r]);
        }
      }
    }
    return;
  }

  // ---- projection ----
  __shared__ float pt0[256];
  __shared__ float pt1[256];
  __shared__ __align__(16) float us[64];
  __shared__ __align__(16) float uk[64];
  __shared__ float cq_s, ck_s;
  const int lane = t & 63;
  const int waveId = (blockIdx.x - binBlocks) * 4 + (t >> 6);
  const int nWaves = projBlocks * 4;

  // fold: us = W^T aw_q, uk = W^T aw_k (read W direct from global, coalesced)
  {
    const int pd = t & 63, og = t >> 6;
    float s0 = 0.f, s1 = 0.f;
#pragma unroll
    for (int oo = 0; oo < 16; ++oo) {
      const int o = og * 16 + oo;
      const float wv = W[o * 64 + pd];
      s0 = fmaf(aw[o], wv, s0);
      s1 = fmaf(aw[64 + o], wv, s1);
    }
    pt0[t] = s0;
    pt1[t] = s1;
  }
  __syncthreads();
  if (t < 64) {
    us[t] = (pt0[t] + pt0[t + 64]) + (pt0[t + 128] + pt0[t + 192]);
    uk[t] = (pt1[t] + pt1[t + 64]) + (pt1[t + 128] + pt1[t + 192]);
    if (t == 0) {
      float c0 = 0.f, c1 = 0.f;
      for (int o = 0; o < 64; ++o) {
        c0 = fmaf(aw[o], pb[o], c0);
        c1 = fmaf(aw[64 + o], pb[o], c1);
      }
      cq_s = c0;
      ck_s = c1;
    }
  }
  __syncthreads();

  // q-side gemv: sq[n] = qnodes[n,:].us + cq (4 nodes per wave-iter)
  {
    const int sub = lane & 15, ng = lane >> 4;
    const float4 uv = ((const float4*)us)[sub];
    const float c = cq_s;
    for (int base = waveId * 4; base < Nq; base += nWaves * 4) {
      const int n = base + ng;
      float s = 0.f;
      if (n < Nq) {
        const float4 x = *(const float4*)(qnodes + (size_t)n * 64 + sub * 4);
        s = x.x * uv.x + x.y * uv.y + x.z * uv.z + x.w * uv.w;
      }
#pragma unroll
      for (int off = 1; off <= 8; off <<= 1) s += __shfl_xor(s, off, 64);
      if (sub == 0 && n < Nq) sq[n] = s + c;
    }
  }

  // k-side folded gemv: sk[n] = kvnodes[n,:].uk + ck
  {
    const int sub = lane & 15, ng = lane >> 4;
    const float4 uv = ((const float4*)uk)[sub];
    const float c = ck_s;
    for (int base = waveId * 4; base < Nk; base += nWaves * 4) {
      const int n = base + ng;
      float s = 0.f;
      if (n < Nk) {
        const float4 x = *(const float4*)(kvnodes + (size_t)n * 64 + sub * 4);
        s = x.x * uv.x + x.y * uv.y + x.z * uv.z + x.w * uv.w;
      }
#pragma unroll
      for (int off = 1; off <= 8; off <<= 1) s += __shfl_xor(s, off, 64);
      if (sub == 0 && n < Nk) sk[n] = s + c;
    }
  }

  // ---- MFMA kv projection ----
  const int c = lane & 15, g = lane >> 4;

  half4_t Bf[4][4];  // [nt][ks] -- compile-time indexed only (full unroll)
  float pbv[4];
#pragma unroll
  for (int nt = 0; nt < 4; ++nt) {
    pbv[nt] = pb[nt * 16 + c];
#pragma unroll
    for (int ks = 0; ks < 4; ++ks) {
      const float4 wv =
          *(const float4*)(W + (size_t)(nt * 16 + c) * 64 + ks * 16 + g * 4);
      half4_t h;
      h[0] = (_Float16)wv.x;
      h[1] = (_Float16)wv.y;
      h[2] = (_Float16)wv.z;
      h[3] = (_Float16)wv.w;
      Bf[nt][ks] = h;
    }
  }

  const int ntiles = (Nk + 15) >> 4;
  for (int tile = waveId; tile < ntiles; tile += nWaves) {
    const int n0 = tile << 4;
    const int arow = n0 + c;
    const bool aok = arow < Nk;
    const float* xr = kvnodes + (size_t)arow * 64 + g * 4;

    half4_t Af[4];
#pragma unroll
    for (int ks = 0; ks < 4; ++ks) {
      const float4 xv =
          aok ? *(const float4*)(xr + ks * 16) : make_float4(0.f, 0.f, 0.f, 0.f);
      half4_t h;
      h[0] = (_Float16)xv.x;
      h[1] = (_Float16)xv.y;
      h[2] = (_Float16)xv.z;
      h[3] = (_Float16)xv.w;
      Af[ks] = h;
    }

    f32x4 acc0 = {pbv[0], pbv[0], pbv[0], pbv[0]};
    f32x4 acc1 = {pbv[1], pbv[1], pbv[1], pbv[1]};
    f32x4 acc2 = {pbv[2], pbv[2], pbv[2], pbv[2]};
    f32x4 acc3 = {pbv[3], pbv[3], pbv[3], pbv[3]};
#pragma unroll
    for (int ks = 0; ks < 4; ++ks) {
      acc0 = __builtin_amdgcn_mfma_f32_16x16x16f16(Af[ks], Bf[0][ks], acc0, 0, 0, 0);
      acc1 = __builtin_amdgcn_mfma_f32_16x16x16f16(Af[ks], Bf[1][ks], acc1, 0, 0, 0);
      acc2 = __builtin_amdgcn_mfma_f32_16x16x16f16(Af[ks], Bf[2][ks], acc2, 0, 0, 0);
      acc3 = __builtin_amdgcn_mfma_f32_16x16x16f16(Af[ks], Bf[3][ks], acc3, 0, 0, 0);
    }

    // epilogue: lane holds D[node n0+g*4+r][o = nt*16 + c] = accN[r]
#pragma unroll
    for (int r = 0; r < 4; ++r) {
      const int node = n0 + g * 4 + r;
      if (node < Nk) {
        const unsigned int u0 =
            ((unsigned int)f2bf(acc1[r]) << 16) | f2bf(acc0[r]);  // dims c, c+16
        const unsigned int u1 =
            ((unsigned int)f2bf(acc3[r]) << 16) | f2bf(acc2[r]);  // dims c+32, c+48
        unsigned int* kp = Kp16 + (size_t)node * 32;
        kp[c] = u0;
        kp[16 + c] = u1;
      }
    }
  }
}

// ---------------------------------------------------------------------------
// sort_agg_kernel: one 512-thr block per 128-qi bucket.
// pairs layout: FIXED per-bucket slots [b][0..KBUF_CAP); count = gcursor[b]
// (clamped). Phase A: register-cache pairs, LDS counting-sort ki -> kibuf.
// Phase B (TRANSPOSED + BATCH-4, validated round 6: 43.6 -> <41us): clamped
// 4-wide edge batches; 4 independent kibuf LDS reads + 8 independent VMEM
// gathers per wait; tail weights selected to exactly 0.f after exp.
// Kp16 word layout (from MFMA proj): uint4 at words 4dg..4dg+3 unpacks to
// dims {obase..+3} (lo) and {obase+16..+19} (hi), obase=(dg&3)*4+(dg>>2)*32.
// ---------------------------------------------------------------------------
__global__ __launch_bounds__(512, 6) void sort_agg_kernel(
    const int2* __restrict__ pairs, const int* __restrict__ gcursor,
    const float* __restrict__ sq, const float* __restrict__ sk,
    const float* __restrict__ ab, const unsigned int* __restrict__ Kp16,
    float* __restrict__ out, int Nq) {
  __shared__ int lcnt[BRANGE];
  __shared__ int lcur[BRANGE];
  __shared__ int lstart[BRANGE + 1];
  __shared__ int kibuf[KBUF_CAP];
  __shared__ int wso2[2];

  const int t = threadIdx.x;
  const int b = blockIdx.x;
  const int qlo = b << BSHIFT;
  int n = gcursor[b];
  if (n > KBUF_CAP) n = KBUF_CAP;  // overflowed reservations dropped at write
  const size_t base = (size_t)b * KBUF_CAP;

  if (t < BRANGE) lcnt[t] = 0;
  __syncthreads();

  // cache this thread's pairs (<= 6 at KBUF_CAP 3072)
  int2 pv[6];
  int np = 0;
#pragma unroll
  for (int r = 0; r < 6; ++r) {
    const int i = t + (r << 9);
    if (i < n) { pv[r] = pairs[base + i]; ++np; }
  }
#pragma unroll
  for (int r = 0; r < 6; ++r)
    if (r < np) atomicAdd(&lcnt[pv[r].x - qlo], 1);
  __syncthreads();

  // exclusive scan of lcnt[0..127] (first 2 waves)
  const int lane = t & 63, wv = t >> 6;
  int v = 0, x = 0;
  if (t < BRANGE) {
    v = lcnt[t];
    x = v;
#pragma unroll
    for (int off = 1; off < 64; off <<= 1) {
      const int y = __shfl_up(x, off, 64);
      if (lane >= off) x += y;
    }
    if (lane == 63) wso2[wv] = x;
  }
  __syncthreads();
  if (t < BRANGE) {
    const int excl = ((wv == 1) ? wso2[0] : 0) + x - v;
    lstart[t] = excl;
    lcur[t] = excl;
    if (t == BRANGE - 1) lstart[BRANGE] = excl + v;
  }
  __syncthreads();

  // scatter ki into kibuf (sorted by local qi)
#pragma unroll
  for (int r = 0; r < 6; ++r)
    if (r < np) kibuf[atomicAdd(&lcur[pv[r].x - qlo], 1)] = pv[r].y;
  __syncthreads();

  // Phase B: transposed aggregation. 8 waves x 8 nodes = 64 nodes per pass.
  const int ng = lane >> 3, dg = lane & 7;
  const float abv = ab[0];
#pragma unroll
  for (int pass = 0; pass < 2; ++pass) {
    const int l = (pass << 6) + (wv << 3) + ng;
    const int node = qlo + l;
    const bool act = node < Nq;
    const int s = act ? lstart[l] : 0;
    const int e = act ? lstart[l + 1] : 0;
    const float sqn = act ? sq[node] + abv : 0.f;

    float acc[8] = {0.f, 0.f, 0.f, 0.f, 0.f, 0.f, 0.f, 0.f};
    float wsum = 0.f;
    const int jm = e - 1;
#pragma unroll 1
    for (int j = s; j < e; j += 4) {
      // 4 independent LDS reads (single lgkm drain)
      const int ka = kibuf[j];
      const int kb = kibuf[min(j + 1, jm)];
      const int kc = kibuf[min(j + 2, jm)];
      const int kd = kibuf[min(j + 3, jm)];
      // 8 independent VMEM gathers (single vm drain)
      const float ea = sk[ka];
      const float eb = sk[kb];
      const float ec = sk[kc];
      const float ed = sk[kd];
      const uint4 ua = *(const uint4*)(Kp16 + (size_t)ka * 32 + (dg << 2));
      const uint4 ub = *(const uint4*)(Kp16 + (size_t)kb * 32 + (dg << 2));
      const uint4 uc = *(const uint4*)(Kp16 + (size_t)kc * 32 + (dg << 2));
      const uint4 ud = *(const uint4*)(Kp16 + (size_t)kd * 32 + (dg << 2));

      float xa = sqn + ea; xa = xa > 0.f ? xa : ALPHA_LEAKY * xa;
      float xb = sqn + eb; xb = xb > 0.f ? xb : ALPHA_LEAKY * xb;
      float xc = sqn + ec; xc = xc > 0.f ? xc : ALPHA_LEAKY * xc;
      float xd = sqn + ed; xd = xd > 0.f ? xd : ALPHA_LEAKY * xd;
      const float wa = __expf(xa);
      const float wb = (j + 1 < e) ? __expf(xb) : 0.f;
      const float wc = (j + 2 < e) ? __expf(xc) : 0.f;
      const float wd = (j + 3 < e) ? __expf(xd) : 0.f;

#define ACC8(W, U)                                             \
  acc[0] = fmaf(W, __uint_as_float(U.x << 16), acc[0]);        \
  acc[1] = fmaf(W, __uint_as_float(U.x & 0xffff0000u), acc[1]);\
  acc[2] = fmaf(W, __uint_as_float(U.y << 16), acc[2]);        \
  acc[3] = fmaf(W, __uint_as_float(U.y & 0xffff0000u), acc[3]);\
  acc[4] = fmaf(W, __uint_as_float(U.z << 16), acc[4]);        \
  acc[5] = fmaf(W, __uint_as_float(U.z & 0xffff0000u), acc[5]);\
  acc[6] = fmaf(W, __uint_as_float(U.w << 16), acc[6]);        \
  acc[7] = fmaf(W, __uint_as_float(U.w & 0xffff0000u), acc[7]);
      ACC8(wa, ua)
      ACC8(wb, ub)
      ACC8(wc, uc)
      ACC8(wd, ud)
#undef ACC8
      wsum += (wa + wb) + (wc + wd);
    }

    if (act) {
      const float inv = 1.0f / (wsum + EPS_F);
      const int obase = ((dg & 3) << 2) + ((dg >> 2) << 5);
      float4 r0 = {acc[0] * inv, acc[2] * inv, acc[4] * inv, acc[6] * inv};
      float4 r1 = {acc[1] * inv, acc[3] * inv, acc[5] * inv, acc[7] * inv};
      float* o = out + (size_t)node * 64 + obase;
      *(float4*)o = r0;
      *(float4*)(o + 16) = r1;
    }
  }
}

extern "C" void kernel_launch(void* const* d_in, const int* in_sizes, int n_in,
                              void* d_out, int out_size, void* d_ws, size_t ws_size,
                              hipStream_t stream) {
  const float* qnodes = (const float*)d_in[0];   // (Nq, 64) f32
  const float* kvnodes = (const float*)d_in[1];  // (Nk, 64) f32
  const int* ei = (const int*)d_in[2];           // (2, E) int32
  const float* W = (const float*)d_in[3];        // (64, 64)
  const float* pb = (const float*)d_in[4];       // (64,)
  const float* aw = (const float*)d_in[5];       // (1, 128): [wq | wk]
  const float* ab = (const float*)d_in[6];       // (1,)

  const int Nq = in_sizes[0] / 64;
  const int Nk = in_sizes[1] / 64;
  const int E = in_sizes[2] / 2;
  const int NB = (Nq + BRANGE - 1) >> BSHIFT;    // 782 at Nq=100000

  const int* eq = ei;
  const int* ek = ei + E;

  // --- workspace layout ---
  char* ws = (char*)d_ws;
  int2* pairs = (int2*)ws;                              // NBMAX*KBUF_CAP int2
  unsigned int* Kp16 =
      (unsigned int*)(pairs + (size_t)NBMAX * KBUF_CAP);// Nk*32 words
  float* sq = (float*)(Kp16 + (size_t)Nk * 32);         // Nq
  float* sk = sq + Nq;                                  // Nk
  int* gcursor = (int*)(sk + Nk);                       // NBMAX

  hipMemsetAsync(gcursor, 0, NBMAX * sizeof(int), stream);

  // --- fused binning + projection (independent; fill the machine together) ---
  const int binBlocks = (E + CHUNK_F - 1) / CHUNK_F;    // 391 at E=1.6M
  const int projBlocks = 768;
  bin_proj_kernel<<<binBlocks + projBlocks, 256, 0, stream>>>(
      eq, ek, gcursor, pairs, E, NB, binBlocks, qnodes, kvnodes, W, pb, aw,
      Kp16, sq, sk, Nq, Nk, projBlocks);

  // --- fused bucket sort + transposed aggregation ---
  sort_agg_kernel<<<NB, 512, 0, stream>>>(pairs, gcursor, sq, sk, ab, Kp16,
                                          (float*)d_out, Nq);
}

// Round 8
// 177.166 us; speedup vs baseline: 1.2802x; 1.0142x over previous
//
#include <hip/hip_runtime.h>

#define ALPHA_LEAKY 0.2f
#define EPS_F 1e-10f

#define BSHIFT 7            // bucket = 128 qi
#define BRANGE 128
#define NBMAX 1024          // max buckets (Nq <= 131072)
#define CHUNK_F 4096        // edges per bin block (256 thr x 16 edges)
#define KBUF_CAP 3072       // per-bucket slot capacity (avg 2048, +22 sigma)

using half4_t = __attribute__((ext_vector_type(4))) _Float16;
using f32x4 = __attribute__((ext_vector_type(4))) float;

// RNE float -> bf16
__device__ __forceinline__ unsigned short f2bf(float x) {
  unsigned int u = __float_as_uint(x);
  return (unsigned short)((u + 0x7fffu + ((u >> 16) & 1u)) >> 16);
}

// ---------------------------------------------------------------------------
// bin_proj_kernel: binning + projection fused (round-7: 48us, VALUBusy 9%,
// MfmaUtil 1%, HBM 22%, Occ 33% -> latency-bound, grid-starved).
// Round-8 changes:
//  (a) k-gemv phase DELETED: sk[n] = sum_o kvproj[n][o]*aw_k[o] is computed
//      exactly from the MFMA accumulators in the epilogue (bias already in
//      acc init) via a 16-lane shfl reduce -- saves a serial latency phase
//      plus a full 25.6MB re-read of kvnodes.
//  (b) projBlocks 768 -> 1664 (grid ~8 blocks/CU) for TLP latency hiding.
//  blocks [0, binBlocks): edge binning into fixed-capacity bucket slots
//    pairs[b][0..KBUF_CAP); gcursor[b] final value IS the bucket count;
//    overflow (statistically never) drops the tail edge.
//  blocks [binBlocks, ...): MFMA projection (validated round 5).
//    Kp16 word layout (PERMUTED): word w = c+16h of node n holds
//    lo16 = bf16(dim c+32h), hi16 = bf16(dim c+32h+16), c=0..15, h=0..1.
// ---------------------------------------------------------------------------
__global__ __launch_bounds__(256, 2) void bin_proj_kernel(
    const int* __restrict__ eq, const int* __restrict__ ek,
    int* __restrict__ gcursor, int2* __restrict__ pairs, int E, int NB,
    int binBlocks,
    const float* __restrict__ qnodes, const float* __restrict__ kvnodes,
    const float* __restrict__ W, const float* __restrict__ pb,
    const float* __restrict__ aw, unsigned int* __restrict__ Kp16,
    float* __restrict__ sq, float* __restrict__ sk,
    int Nq, int Nk, int projBlocks) {
  const int t = threadIdx.x;

  if (blockIdx.x < binBlocks) {
    // ---- binning ----
    __shared__ int lcnt[NBMAX];
    __shared__ int lbase[NBMAX];
    for (int i = t; i < NBMAX; i += 256) lcnt[i] = 0;
    __syncthreads();

    const int cbase = blockIdx.x * CHUNK_F;
    int4 qv[4], kv[4];
#pragma unroll
    for (int j = 0; j < 4; ++j) {
      const int e0 = cbase + (((j << 8) + t) << 2);
      if (e0 + 3 < E) {
        qv[j] = *(const int4*)(eq + e0);
        kv[j] = *(const int4*)(ek + e0);
      } else {
        int tq[4] = {-1, -1, -1, -1}, tk[4] = {0, 0, 0, 0};
        for (int r = 0; r < 4; ++r)
          if (e0 + r < E) { tq[r] = eq[e0 + r]; tk[r] = ek[e0 + r]; }
        qv[j] = make_int4(tq[0], tq[1], tq[2], tq[3]);
        kv[j] = make_int4(tk[0], tk[1], tk[2], tk[3]);
      }
      if (qv[j].x >= 0) atomicAdd(&lcnt[qv[j].x >> BSHIFT], 1);
      if (qv[j].y >= 0) atomicAdd(&lcnt[qv[j].y >> BSHIFT], 1);
      if (qv[j].z >= 0) atomicAdd(&lcnt[qv[j].z >> BSHIFT], 1);
      if (qv[j].w >= 0) atomicAdd(&lcnt[qv[j].w >> BSHIFT], 1);
    }
    __syncthreads();
    for (int i = t; i < NB; i += 256) {
      lbase[i] = lcnt[i] ? atomicAdd(&gcursor[i], lcnt[i]) : 0;
      lcnt[i] = 0;
    }
    __syncthreads();
#pragma unroll
    for (int j = 0; j < 4; ++j) {
      const int qs[4] = {qv[j].x, qv[j].y, qv[j].z, qv[j].w};
      const int ks[4] = {kv[j].x, kv[j].y, kv[j].z, kv[j].w};
#pragma unroll
      for (int r = 0; r < 4; ++r) {
        if (qs[r] >= 0) {
          const int b = qs[r] >> BSHIFT;
          const int idx = lbase[b] + atomicAdd(&lcnt[b], 1);
          if (idx < KBUF_CAP)
            pairs[(size_t)b * KBUF_CAP + idx] = make_int2(qs[r], ks[r]);
        }
      }
    }
    return;
  }

  // ---- projection ----
  __shared__ float pt0[256];
  __shared__ __align__(16) float us[64];
  __shared__ float cq_s;
  const int lane = t & 63;
  const int waveId = (blockIdx.x - binBlocks) * 4 + (t >> 6);
  const int nWaves = projBlocks * 4;

  // fold: us = W^T aw_q (read W direct from global, coalesced)
  {
    const int pd = t & 63, og = t >> 6;
    float s0 = 0.f;
#pragma unroll
    for (int oo = 0; oo < 16; ++oo) {
      const int o = og * 16 + oo;
      s0 = fmaf(aw[o], W[o * 64 + pd], s0);
    }
    pt0[t] = s0;
  }
  __syncthreads();
  if (t < 64) {
    us[t] = (pt0[t] + pt0[t + 64]) + (pt0[t + 128] + pt0[t + 192]);
    if (t == 0) {
      float c0 = 0.f;
      for (int o = 0; o < 64; ++o) c0 = fmaf(aw[o], pb[o], c0);
      cq_s = c0;
    }
  }
  __syncthreads();

  // q-side gemv: sq[n] = qnodes[n,:].us + cq (4 nodes per wave-iter)
  {
    const int sub = lane & 15, ng = lane >> 4;
    const float4 uv = ((const float4*)us)[sub];
    const float c = cq_s;
    for (int base = waveId * 4; base < Nq; base += nWaves * 4) {
      const int n = base + ng;
      float s = 0.f;
      if (n < Nq) {
        const float4 x = *(const float4*)(qnodes + (size_t)n * 64 + sub * 4);
        s = x.x * uv.x + x.y * uv.y + x.z * uv.z + x.w * uv.w;
      }
#pragma unroll
      for (int off = 1; off <= 8; off <<= 1) s += __shfl_xor(s, off, 64);
      if (sub == 0 && n < Nq) sq[n] = s + c;
    }
  }

  // ---- MFMA kv projection (+ fused sk epilogue) ----
  const int c = lane & 15, g = lane >> 4;

  half4_t Bf[4][4];  // [nt][ks] -- compile-time indexed only (full unroll)
  float pbv[4];
#pragma unroll
  for (int nt = 0; nt < 4; ++nt) {
    pbv[nt] = pb[nt * 16 + c];
#pragma unroll
    for (int ks = 0; ks < 4; ++ks) {
      const float4 wv =
          *(const float4*)(W + (size_t)(nt * 16 + c) * 64 + ks * 16 + g * 4);
      half4_t h;
      h[0] = (_Float16)wv.x;
      h[1] = (_Float16)wv.y;
      h[2] = (_Float16)wv.z;
      h[3] = (_Float16)wv.w;
      Bf[nt][ks] = h;
    }
  }
  // aw_k weights for this lane's 4 output dims (c, c+16, c+32, c+48)
  const float a0 = aw[64 + c], a1 = aw[80 + c], a2 = aw[96 + c],
              a3 = aw[112 + c];

  const int ntiles = (Nk + 15) >> 4;
  for (int tile = waveId; tile < ntiles; tile += nWaves) {
    const int n0 = tile << 4;
    const int arow = n0 + c;
    const bool aok = arow < Nk;
    const float* xr = kvnodes + (size_t)arow * 64 + g * 4;

    half4_t Af[4];
#pragma unroll
    for (int ks = 0; ks < 4; ++ks) {
      const float4 xv =
          aok ? *(const float4*)(xr + ks * 16) : make_float4(0.f, 0.f, 0.f, 0.f);
      half4_t h;
      h[0] = (_Float16)xv.x;
      h[1] = (_Float16)xv.y;
      h[2] = (_Float16)xv.z;
      h[3] = (_Float16)xv.w;
      Af[ks] = h;
    }

    f32x4 acc0 = {pbv[0], pbv[0], pbv[0], pbv[0]};
    f32x4 acc1 = {pbv[1], pbv[1], pbv[1], pbv[1]};
    f32x4 acc2 = {pbv[2], pbv[2], pbv[2], pbv[2]};
    f32x4 acc3 = {pbv[3], pbv[3], pbv[3], pbv[3]};
#pragma unroll
    for (int ks = 0; ks < 4; ++ks) {
      acc0 = __builtin_amdgcn_mfma_f32_16x16x16f16(Af[ks], Bf[0][ks], acc0, 0, 0, 0);
      acc1 = __builtin_amdgcn_mfma_f32_16x16x16f16(Af[ks], Bf[1][ks], acc1, 0, 0, 0);
      acc2 = __builtin_amdgcn_mfma_f32_16x16x16f16(Af[ks], Bf[2][ks], acc2, 0, 0, 0);
      acc3 = __builtin_amdgcn_mfma_f32_16x16x16f16(Af[ks], Bf[3][ks], acc3, 0, 0, 0);
    }

    // Kp16 epilogue: lane holds D[node n0+g*4+r][o = nt*16 + c] = accN[r]
#pragma unroll
    for (int r = 0; r < 4; ++r) {
      const int node = n0 + g * 4 + r;
      if (node < Nk) {
        const unsigned int u0 =
            ((unsigned int)f2bf(acc1[r]) << 16) | f2bf(acc0[r]);  // dims c, c+16
        const unsigned int u1 =
            ((unsigned int)f2bf(acc3[r]) << 16) | f2bf(acc2[r]);  // dims c+32, c+48
        unsigned int* kp = Kp16 + (size_t)node * 32;
        kp[c] = u0;
        kp[16 + c] = u1;
      }
    }

    // sk epilogue: ws_r = sum over 64 dims of kvproj * aw_k  (bias included
    // via acc init). Per-lane partial over its 4 dims, then reduce across
    // the 16 c-lanes of this g-group (xor 1,2,4,8 stays in-group).
    float ws0 = acc0[0] * a0 + acc1[0] * a1 + acc2[0] * a2 + acc3[0] * a3;
    float ws1 = acc0[1] * a0 + acc1[1] * a1 + acc2[1] * a2 + acc3[1] * a3;
    float ws2 = acc0[2] * a0 + acc1[2] * a1 + acc2[2] * a2 + acc3[2] * a3;
    float ws3 = acc0[3] * a0 + acc1[3] * a1 + acc2[3] * a2 + acc3[3] * a3;
#pragma unroll
    for (int off = 1; off <= 8; off <<= 1) {
      ws0 += __shfl_xor(ws0, off, 64);
      ws1 += __shfl_xor(ws1, off, 64);
      ws2 += __shfl_xor(ws2, off, 64);
      ws3 += __shfl_xor(ws3, off, 64);
    }
    if (c == 0) {
      const int nb4 = n0 + g * 4;
      if (nb4 + 3 < Nk) {
        *(float4*)(sk + nb4) = make_float4(ws0, ws1, ws2, ws3);
      } else {
        if (nb4 + 0 < Nk) sk[nb4 + 0] = ws0;
        if (nb4 + 1 < Nk) sk[nb4 + 1] = ws1;
        if (nb4 + 2 < Nk) sk[nb4 + 2] = ws2;
        if (nb4 + 3 < Nk) sk[nb4 + 3] = ws3;
      }
    }
  }
}

// ---------------------------------------------------------------------------
// sort_agg_kernel: one 512-thr block per 128-qi bucket.
// pairs layout: FIXED per-bucket slots [b][0..KBUF_CAP); count = gcursor[b]
// (clamped). Phase A: register-cache pairs, LDS counting-sort ki -> kibuf.
// Phase B (TRANSPOSED + BATCH-4, validated round 6: 43.6 -> <41us): clamped
// 4-wide edge batches; 4 independent kibuf LDS reads + 8 independent VMEM
// gathers per wait; tail weights selected to exactly 0.f after exp.
// Kp16 word layout (from MFMA proj): uint4 at words 4dg..4dg+3 unpacks to
// dims {obase..+3} (lo) and {obase+16..+19} (hi), obase=(dg&3)*4+(dg>>2)*32.
// ---------------------------------------------------------------------------
__global__ __launch_bounds__(512, 6) void sort_agg_kernel(
    const int2* __restrict__ pairs, const int* __restrict__ gcursor,
    const float* __restrict__ sq, const float* __restrict__ sk,
    const float* __restrict__ ab, const unsigned int* __restrict__ Kp16,
    float* __restrict__ out, int Nq) {
  __shared__ int lcnt[BRANGE];
  __shared__ int lcur[BRANGE];
  __shared__ int lstart[BRANGE + 1];
  __shared__ int kibuf[KBUF_CAP];
  __shared__ int wso2[2];

  const int t = threadIdx.x;
  const int b = blockIdx.x;
  const int qlo = b << BSHIFT;
  int n = gcursor[b];
  if (n > KBUF_CAP) n = KBUF_CAP;  // overflowed reservations dropped at write
  const size_t base = (size_t)b * KBUF_CAP;

  if (t < BRANGE) lcnt[t] = 0;
  __syncthreads();

  // cache this thread's pairs (<= 6 at KBUF_CAP 3072)
  int2 pv[6];
  int np = 0;
#pragma unroll
  for (int r = 0; r < 6; ++r) {
    const int i = t + (r << 9);
    if (i < n) { pv[r] = pairs[base + i]; ++np; }
  }
#pragma unroll
  for (int r = 0; r < 6; ++r)
    if (r < np) atomicAdd(&lcnt[pv[r].x - qlo], 1);
  __syncthreads();

  // exclusive scan of lcnt[0..127] (first 2 waves)
  const int lane = t & 63, wv = t >> 6;
  int v = 0, x = 0;
  if (t < BRANGE) {
    v = lcnt[t];
    x = v;
#pragma unroll
    for (int off = 1; off < 64; off <<= 1) {
      const int y = __shfl_up(x, off, 64);
      if (lane >= off) x += y;
    }
    if (lane == 63) wso2[wv] = x;
  }
  __syncthreads();
  if (t < BRANGE) {
    const int excl = ((wv == 1) ? wso2[0] : 0) + x - v;
    lstart[t] = excl;
    lcur[t] = excl;
    if (t == BRANGE - 1) lstart[BRANGE] = excl + v;
  }
  __syncthreads();

  // scatter ki into kibuf (sorted by local qi)
#pragma unroll
  for (int r = 0; r < 6; ++r)
    if (r < np) kibuf[atomicAdd(&lcur[pv[r].x - qlo], 1)] = pv[r].y;
  __syncthreads();

  // Phase B: transposed aggregation. 8 waves x 8 nodes = 64 nodes per pass.
  const int ng = lane >> 3, dg = lane & 7;
  const float abv = ab[0];
#pragma unroll
  for (int pass = 0; pass < 2; ++pass) {
    const int l = (pass << 6) + (wv << 3) + ng;
    const int node = qlo + l;
    const bool act = node < Nq;
    const int s = act ? lstart[l] : 0;
    const int e = act ? lstart[l + 1] : 0;
    const float sqn = act ? sq[node] + abv : 0.f;

    float acc[8] = {0.f, 0.f, 0.f, 0.f, 0.f, 0.f, 0.f, 0.f};
    float wsum = 0.f;
    const int jm = e - 1;
#pragma unroll 1
    for (int j = s; j < e; j += 4) {
      // 4 independent LDS reads (single lgkm drain)
      const int ka = kibuf[j];
      const int kb = kibuf[min(j + 1, jm)];
      const int kc = kibuf[min(j + 2, jm)];
      const int kd = kibuf[min(j + 3, jm)];
      // 8 independent VMEM gathers (single vm drain)
      const float ea = sk[ka];
      const float eb = sk[kb];
      const float ec = sk[kc];
      const float ed = sk[kd];
      const uint4 ua = *(const uint4*)(Kp16 + (size_t)ka * 32 + (dg << 2));
      const uint4 ub = *(const uint4*)(Kp16 + (size_t)kb * 32 + (dg << 2));
      const uint4 uc = *(const uint4*)(Kp16 + (size_t)kc * 32 + (dg << 2));
      const uint4 ud = *(const uint4*)(Kp16 + (size_t)kd * 32 + (dg << 2));

      float xa = sqn + ea; xa = xa > 0.f ? xa : ALPHA_LEAKY * xa;
      float xb = sqn + eb; xb = xb > 0.f ? xb : ALPHA_LEAKY * xb;
      float xc = sqn + ec; xc = xc > 0.f ? xc : ALPHA_LEAKY * xc;
      float xd = sqn + ed; xd = xd > 0.f ? xd : ALPHA_LEAKY * xd;
      const float wa = __expf(xa);
      const float wb = (j + 1 < e) ? __expf(xb) : 0.f;
      const float wc = (j + 2 < e) ? __expf(xc) : 0.f;
      const float wd = (j + 3 < e) ? __expf(xd) : 0.f;

#define ACC8(W, U)                                             \
  acc[0] = fmaf(W, __uint_as_float(U.x << 16), acc[0]);        \
  acc[1] = fmaf(W, __uint_as_float(U.x & 0xffff0000u), acc[1]);\
  acc[2] = fmaf(W, __uint_as_float(U.y << 16), acc[2]);        \
  acc[3] = fmaf(W, __uint_as_float(U.y & 0xffff0000u), acc[3]);\
  acc[4] = fmaf(W, __uint_as_float(U.z << 16), acc[4]);        \
  acc[5] = fmaf(W, __uint_as_float(U.z & 0xffff0000u), acc[5]);\
  acc[6] = fmaf(W, __uint_as_float(U.w << 16), acc[6]);        \
  acc[7] = fmaf(W, __uint_as_float(U.w & 0xffff0000u), acc[7]);
      ACC8(wa, ua)
      ACC8(wb, ub)
      ACC8(wc, uc)
      ACC8(wd, ud)
#undef ACC8
      wsum += (wa + wb) + (wc + wd);
    }

    if (act) {
      const float inv = 1.0f / (wsum + EPS_F);
      const int obase = ((dg & 3) << 2) + ((dg >> 2) << 5);
      float4 r0 = {acc[0] * inv, acc[2] * inv, acc[4] * inv, acc[6] * inv};
      float4 r1 = {acc[1] * inv, acc[3] * inv, acc[5] * inv, acc[7] * inv};
      float* o = out + (size_t)node * 64 + obase;
      *(float4*)o = r0;
      *(float4*)(o + 16) = r1;
    }
  }
}

extern "C" void kernel_launch(void* const* d_in, const int* in_sizes, int n_in,
                              void* d_out, int out_size, void* d_ws, size_t ws_size,
                              hipStream_t stream) {
  const float* qnodes = (const float*)d_in[0];   // (Nq, 64) f32
  const float* kvnodes = (const float*)d_in[1];  // (Nk, 64) f32
  const int* ei = (const int*)d_in[2];           // (2, E) int32
  const float* W = (const float*)d_in[3];        // (64, 64)
  const float* pb = (const float*)d_in[4];       // (64,)
  const float* aw = (const float*)d_in[5];       // (1, 128): [wq | wk]
  const float* ab = (const float*)d_in[6];       // (1,)

  const int Nq = in_sizes[0] / 64;
  const int Nk = in_sizes[1] / 64;
  const int E = in_sizes[2] / 2;
  const int NB = (Nq + BRANGE - 1) >> BSHIFT;    // 782 at Nq=100000

  const int* eq = ei;
  const int* ek = ei + E;

  // --- workspace layout ---
  char* ws = (char*)d_ws;
  int2* pairs = (int2*)ws;                              // NBMAX*KBUF_CAP int2
  unsigned int* Kp16 =
      (unsigned int*)(pairs + (size_t)NBMAX * KBUF_CAP);// Nk*32 words
  float* sq = (float*)(Kp16 + (size_t)Nk * 32);         // Nq
  float* sk = sq + Nq;                                  // Nk
  int* gcursor = (int*)(sk + Nk);                       // NBMAX

  hipMemsetAsync(gcursor, 0, NBMAX * sizeof(int), stream);

  // --- fused binning + projection (independent; fill the machine together) ---
  const int binBlocks = (E + CHUNK_F - 1) / CHUNK_F;    // 391 at E=1.6M
  const int projBlocks = 1664;
  bin_proj_kernel<<<binBlocks + projBlocks, 256, 0, stream>>>(
      eq, ek, gcursor, pairs, E, NB, binBlocks, qnodes, kvnodes, W, pb, aw,
      Kp16, sq, sk, Nq, Nk, projBlocks);

  // --- fused bucket sort + transposed aggregation ---
  sort_agg_kernel<<<NB, 512, 0, stream>>>(pairs, gcursor, sq, sk, ab, Kp16,
                                          (float*)d_out, Nq);
}